// Round 1
// 423.028 us; speedup vs baseline: 1.1928x; 1.1928x over previous
//
#include <hip/hip_runtime.h>
#include <hip/hip_bf16.h>

#define NN    200000
#define EE    3200000
#define DDIMC 768

#define NB    25        // node buckets
#define BSH   13
#define BSZ   8192      // nodes per bucket -> 32KB LDS histogram
#define CC    12        // edge chunks per bucket
#define NI4   800000    // EE/4 int4s
#define BW4   2048      // int4 window (32KB)
#define HTH   1024      // histogram block threads
#define PARTW (NB * CC * BSZ)

#define NDBLK 782       // ceil(NN/256)
#define XBLOCKS 1024
#define CAPL  4096

// ---- workspace layout (word offsets) ----
#define P_PART  0
#define P_HIST  PARTW                    // 65536 i32 (zeroed)
#define P_CANDN (P_HIST + 65536)         // 8 (zeroed)
#define P_S8    (P_CANDN + 8)            // 512 (zeroed)
#define ZERO_LEN (65536 + 8 + 512)       // from P_HIST
#define P_FLAG  (P_S8 + 512)
#define P_THR   (P_FLAG + 8)
#define P_SV    (P_THR + 8)
#define P_D     (P_SV + 64)
#define P_DIS   (P_D + 256)
#define P_C     (P_DIS + NN)
#define P_SCORE (P_C + NN)
#define P_CKEY  (P_SCORE + NN)
#define P_CIDX  (P_CKEY + 4096)
#define P_XT    (P_CIDX + 4096)
#define P_WW    (P_XT + 4096)
#define P_G     (P_WW + 4096)            // 256 f32
#define P_LNV   (P_G + 256)              // 512 f32
#define P_H1    (P_LNV + 512)            // 256 f32

// ---- helpers (proven) ----
__device__ __forceinline__ float ldf(const void* p, int i, int bf) {
  if (bf) return __bfloat162float(((const __hip_bfloat16*)p)[i]);
  return ((const float*)p)[i];
}
__device__ __forceinline__ void stf(void* p, int i, float v, int bf) {
  if (bf) ((__hip_bfloat16*)p)[i] = __float2bfloat16(v);
  else ((float*)p)[i] = v;
}
__device__ __forceinline__ float bfu(unsigned u) {   // low 16 bits -> bf16 value
  return __uint_as_float(u << 16);
}
__device__ __forceinline__ float wsum(float v) {
#pragma unroll
  for (int m = 32; m >= 1; m >>= 1) v += __shfl_xor(v, m, 64);
  return v;
}
__device__ __forceinline__ int wsumi(int v) {
#pragma unroll
  for (int m = 32; m >= 1; m >>= 1) v += __shfl_xor(v, m, 64);
  return v;
}
__device__ __forceinline__ unsigned sortkey(float f) {
  unsigned u = __float_as_uint(f);
  return (u & 0x80000000u) ? ~u : (u | 0x80000000u);
}

// ---- dtype detector (proven) ----
__global__ void k_detect(const unsigned short* x16, int* flag) {
  __shared__ int cnt;
  if (threadIdx.x == 0) cnt = 0;
  __syncthreads();
  int ok = 0;
  for (int k = threadIdx.x; k < 512; k += 256) {
    unsigned short u = x16[2 * k];
    int e = (u >> 7) & 0xFF;
    if (u == 0 || (e >= 100 && e <= 150)) ok++;
  }
  atomicAdd(&cnt, ok);
  __syncthreads();
  if (threadIdx.x == 0) flag[0] = (cnt >= 400) ? 1 : 0;
}

// ---- bucketed degree histogram (proven) ----
__global__ void __launch_bounds__(HTH) k_hcol(const int* __restrict__ col, int* __restrict__ part) {
  __shared__ int lh[BSZ];
  int t = threadIdx.x;
  int b = blockIdx.x / CC, j = blockIdx.x % CC;
  for (int k = t; k < BSZ; k += HTH) lh[k] = 0;
  __syncthreads();
  int base = b << BSH;
  const int4* c4 = (const int4*)col;
  for (int w0 = j * BW4; w0 < NI4; w0 += CC * BW4) {
    int end = w0 + BW4; if (end > NI4) end = NI4;
    for (int i = w0 + t; i < end; i += HTH) {
      int4 v = c4[i];
      int a0 = v.x - base, a1 = v.y - base, a2 = v.z - base, a3 = v.w - base;
      if ((unsigned)a0 < (unsigned)BSZ) atomicAdd(&lh[a0], 1);
      if ((unsigned)a1 < (unsigned)BSZ) atomicAdd(&lh[a1], 1);
      if ((unsigned)a2 < (unsigned)BSZ) atomicAdd(&lh[a2], 1);
      if ((unsigned)a3 < (unsigned)BSZ) atomicAdd(&lh[a3], 1);
    }
  }
  __syncthreads();
  int* dst = part + (size_t)blockIdx.x * BSZ;
  for (int k = t; k < BSZ; k += HTH) dst[k] = lh[k];
}

// ---- reduce degree partials -> dis; doc matvec on extra blocks (proven) ----
__global__ void k_redA(const int* __restrict__ part, float* __restrict__ dis,
                       const void* docf, const void* dw, const void* db,
                       float* __restrict__ d, const int* flagp) {
  if (blockIdx.x < NDBLK) {
    int i = blockIdx.x * 256 + threadIdx.x;
    if (i < NN) {
      int b = i >> BSH, k = i & (BSZ - 1);
      const int* p = part + (size_t)b * CC * BSZ + k;
      int deg = 1;
#pragma unroll
      for (int j = 0; j < CC; j++) deg += p[(size_t)j * BSZ];
      dis[i] = rsqrtf((float)deg);
    }
  } else {
    int flag = flagp[0];
    int o = (blockIdx.x - NDBLK) * 4 + (threadIdx.x >> 6);
    int lane = threadIdx.x & 63;
    float acc = 0.f;
    for (int k = lane; k < DDIMC; k += 64) acc += ldf(docf, k, flag) * ldf(dw, o * DDIMC + k, flag);
    acc = wsum(acc);
    if (lane == 0) d[o] = fmaxf(acc + ldf(db, o, flag), 0.0f);
  }
}

// ---- weighted bucket histogram over row, weight = dis[col] (proven) ----
__global__ void __launch_bounds__(HTH) k_hrow(const int* __restrict__ row, const int* __restrict__ col,
                                              const float* __restrict__ dis, float* __restrict__ part) {
  __shared__ float lh[BSZ];
  int t = threadIdx.x;
  int b = blockIdx.x / CC, j = blockIdx.x % CC;
  for (int k = t; k < BSZ; k += HTH) lh[k] = 0.f;
  __syncthreads();
  int base = b << BSH;
  const int4* r4 = (const int4*)row;
  const int4* c4 = (const int4*)col;
  for (int w0 = j * BW4; w0 < NI4; w0 += CC * BW4) {
    int end = w0 + BW4; if (end > NI4) end = NI4;
    for (int i = w0 + t; i < end; i += HTH) {
      int4 r = r4[i];
      int4 c = c4[i];
      int a0 = r.x - base, a1 = r.y - base, a2 = r.z - base, a3 = r.w - base;
      if ((unsigned)a0 < (unsigned)BSZ) atomicAdd(&lh[a0], dis[c.x]);
      if ((unsigned)a1 < (unsigned)BSZ) atomicAdd(&lh[a1], dis[c.y]);
      if ((unsigned)a2 < (unsigned)BSZ) atomicAdd(&lh[a2], dis[c.z]);
      if ((unsigned)a3 < (unsigned)BSZ) atomicAdd(&lh[a3], dis[c.w]);
    }
  }
  __syncthreads();
  float* dst = part + (size_t)blockIdx.x * BSZ;
  for (int k = t; k < BSZ; k += HTH) dst[k] = lh[k];
}

// ---- reduce weighted partials -> c_i = dis_i*tacc_i + dis_i^2 (proven) ----
__global__ void k_redB(const float* __restrict__ part, const float* __restrict__ dis,
                       float* __restrict__ c) {
  int i = blockIdx.x * 256 + threadIdx.x;
  if (i < NN) {
    int b = i >> BSH, k = i & (BSZ - 1);
    const float* p = part + (size_t)b * CC * BSZ + k;
    float s = 0.f;
#pragma unroll
    for (int j = 0; j < CC; j++) s += p[(size_t)j * BSZ];
    float dv = dis[i];
    c[i] = dv * s + dv * dv;
  }
}

// ---- fused x pass (proven) ----
__global__ void k_x(const void* x, const void* pw, const float* __restrict__ c,
                    float* __restrict__ score, int* __restrict__ hist,
                    float* __restrict__ s8, const int* flagp) {
  __shared__ float sred[4][64];
  int flag = flagp[0];
  int t = threadIdx.x;
  int lane = t & 63;
  int w = t >> 6;
  int wid = (blockIdx.x * 256 + t) >> 6;
  int nw = (gridDim.x * 256) >> 6;
  float pwl = ldf(pw, lane, flag);
  float inv = 1.0f / sqrtf(wsum(pwl * pwl));
  float sacc = 0.f;
  for (int r = wid; r < NN; r += nw) {
    float xv = ldf(x, r * 64 + lane, flag);
    float dot = wsum(xv * pwl);
    sacc += c[r] * xv;
    if (lane == 0) {
      float sc = dot * inv;
      score[r] = sc;
      atomicAdd(&hist[sortkey(sc) >> 16], 1);
    }
  }
  sred[w][lane] = sacc;
  __syncthreads();
  if (w == 0)
    atomicAdd(&s8[(blockIdx.x & 7) * 64 + lane],
              sred[0][lane] + sred[1][lane] + sred[2][lane] + sred[3][lane]);
}

// ---- threshold (proven) ----
__global__ void k_thresh(const int* __restrict__ hist, int* __restrict__ thrB,
                         const float* __restrict__ s8, float* __restrict__ svec) {
  __shared__ int part[256];
  __shared__ int segl[256];
  __shared__ int res2[2];
  int t = threadIdx.x, w = t >> 6, lane = t & 63;
  if (t < 64) {
    float a = 0.f;
    for (int r = 0; r < 8; r++) a += s8[r * 64 + t];
    svec[t] = a;
  }
  for (int m = w; m < 256; m += 4) {
    const int* hb = &hist[m * 256];
    int a = hb[lane] + hb[lane + 64] + hb[lane + 128] + hb[lane + 192];
    a = wsumi(a);
    if (lane == 0) part[m] = a;
  }
  __syncthreads();
  if (t == 0) {
    int acc = 0, seg = 0, above = 0;
    for (int b = 255; b >= 0; b--) {
      if (acc + part[b] >= 64) { seg = b; above = acc; break; }
      acc += part[b];
    }
    res2[0] = seg; res2[1] = above;
  }
  __syncthreads();
  segl[t] = hist[res2[0] * 256 + t];
  __syncthreads();
  if (t == 0) {
    int acc = res2[1], B = res2[0] * 256;
    for (int j = 255; j >= 0; j--) {
      acc += segl[j];
      if (acc >= 64) { B = res2[0] * 256 + j; break; }
    }
    thrB[0] = B;
  }
}

// ---- collect (proven) ----
__global__ void k_collect(const float* __restrict__ score, const int* __restrict__ thrB,
                          int* __restrict__ candn, unsigned* __restrict__ ckey,
                          int* __restrict__ cidx) {
  int i = blockIdx.x * blockDim.x + threadIdx.x;
  if (i >= NN) return;
  unsigned u = sortkey(score[i]);
  if ((int)(u >> 16) >= thrB[0]) {
    int p = atomicAdd(candn, 1);
    if (p < CAPL) { ckey[p] = u; cidx[p] = i; }
  }
}

// ---- top-64 (proven) ----
__global__ void k_top(const int* __restrict__ candn, const unsigned* __restrict__ ckey,
                      const int* __restrict__ cidx, const void* x,
                      float* __restrict__ xt, const int* flagp) {
  __shared__ unsigned long long keys[CAPL];
  __shared__ int perm[64];
  __shared__ float ts[64];
  int flag = flagp[0];
  int t = threadIdx.x;
  int M = candn[0];
  if (M > CAPL) M = CAPL;
  for (int j = t; j < M; j += 256)
    keys[j] = (((unsigned long long)ckey[j]) << 32) |
              (unsigned long long)(0xFFFFFFFFu - (unsigned)cidx[j]);
  __syncthreads();
  for (int j = t; j < M; j += 256) {
    unsigned long long k = keys[j];
    int rank = 0;
    for (int i = 0; i < M; i++) rank += (keys[i] > k) ? 1 : 0;
    if (rank < 64) {
      unsigned ku = (unsigned)(k >> 32);
      unsigned idx = 0xFFFFFFFFu - (unsigned)(k & 0xFFFFFFFFu);
      perm[rank] = (int)idx;
      unsigned bits = (ku & 0x80000000u) ? (ku ^ 0x80000000u) : ~ku;
      ts[rank] = tanhf(__uint_as_float(bits));
    }
  }
  __syncthreads();
  for (int q = t; q < 4096; q += 256) {
    int j = q >> 6, f = q & 63;
    xt[q] = ldf(x, perm[j] * 64 + f, flag) * ts[j];
  }
}

// ---- GRU (REWORKED): coalesced vectorized weight staging, LDS-side transpose ----
// Old version did the transpose on the global-read side (stride-64-float scalar
// loads -> 64 cache lines per wave, 16x overfetch, latency-serialized at 0.66%
// occupancy -> 97us). Now: linear float4/uint4 reads (16B/lane coalesced),
// transpose via LDS scatter, stride 193 (192%32==0 is worst-case banking),
// both matrices staged concurrently behind a single barrier.
#define GS 193
__device__ __forceinline__ void stage_w(const void* src, float* dst, int flag, int t) {
  if (flag) {
    const uint4* s4 = (const uint4*)src;          // 12288 bf16 = 1536 uint4
    for (int k = t; k < 1536; k += 256) {
      uint4 u = s4[k];
      int e = k << 3; int o = e >> 6, f = e & 63; // 8 elems share o, f..f+7
      float* d = &dst[f * GS + o];
      d[0]      = bfu(u.x & 0xffff); d[GS]     = bfu(u.x >> 16);
      d[2 * GS] = bfu(u.y & 0xffff); d[3 * GS] = bfu(u.y >> 16);
      d[4 * GS] = bfu(u.z & 0xffff); d[5 * GS] = bfu(u.z >> 16);
      d[6 * GS] = bfu(u.w & 0xffff); d[7 * GS] = bfu(u.w >> 16);
    }
  } else {
    const float4* s4 = (const float4*)src;        // 12288 f32 = 3072 float4
    for (int k = t; k < 3072; k += 256) {
      float4 v = s4[k];
      int e = k << 2; int o = e >> 6, f = e & 63; // 4 elems share o, f..f+3
      float* d = &dst[f * GS + o];
      d[0] = v.x; d[GS] = v.y; d[2 * GS] = v.z; d[3 * GS] = v.w;
    }
  }
}

__global__ void k_gru(const float* __restrict__ xt, const void* h0g, const void* wihg,
                      const void* whhg, const void* bihg, const void* bhhg,
                      float* __restrict__ Wout, const int* flagp) {
  __shared__ float wb1[64 * GS];   // wih^T  [f][o], 49.4KB
  __shared__ float wb2[64 * GS];   // whh^T  [f][o], 49.4KB
  __shared__ float xtr[256];
  __shared__ float h0r[256];
  int flag = flagp[0];
  int t = threadIdx.x;
  int j0 = blockIdx.x * 4;
  { int jj = t >> 6, f = t & 63;
    xtr[t] = xt[(j0 + jj) * 64 + f];
    h0r[t] = ldf(h0g, (j0 + jj) * 64 + f, flag); }
  stage_w(wihg, wb1, flag, t);
  stage_w(whhg, wb2, flag, t);
  __syncthreads();
  int jl = t >> 6, c2 = t & 63;
  float xr = 0, xz = 0, xn = 0, hr = 0, hz = 0, hn = 0;
#pragma unroll 4
  for (int f = 0; f < 64; f++) {
    float xv = xtr[jl * 64 + f];
    float hv = h0r[jl * 64 + f];
    const float* w1 = &wb1[f * GS];
    const float* w2 = &wb2[f * GS];
    xr += xv * w1[c2]; xz += xv * w1[64 + c2]; xn += xv * w1[128 + c2];
    hr += hv * w2[c2]; hz += hv * w2[64 + c2]; hn += hv * w2[128 + c2];
  }
  xr += ldf(bihg, c2, flag); xz += ldf(bihg, 64 + c2, flag); xn += ldf(bihg, 128 + c2, flag);
  hr += ldf(bhhg, c2, flag); hz += ldf(bhhg, 64 + c2, flag); hn += ldf(bhhg, 128 + c2, flag);
  float rg = 1.f / (1.f + expf(-(xr + hr)));
  float zg = 1.f / (1.f + expf(-(xz + hz)));
  float nc = tanhf(xn + rg * hn);
  Wout[(j0 + jl) * 64 + c2] = (1.f - zg) * nc + zg * h0r[jl * 64 + c2];
}

// ---- tail stage 1: g[o] = pooled @ gnn_fc_w.T + gnn_fc_b  (64 blocks) ----
__global__ void k_g(const float* __restrict__ svec, const float* __restrict__ Wm,
                    const void* gw, const void* gb, float* __restrict__ g,
                    const int* flagp) {
  __shared__ float pooled[64];
  int flag = flagp[0];
  int t = threadIdx.x, w = t >> 6, lane = t & 63;
  if (t < 64) {
    float a = 0.f;
    for (int f = 0; f < 64; f++) a += svec[f] * Wm[f * 64 + t];
    pooled[t] = a * (1.0f / (float)NN);
  }
  __syncthreads();
  int o = blockIdx.x * 4 + w;      // 0..255
  float acc = pooled[lane] * ldf(gw, o * 64 + lane, flag);
  acc = wsum(acc);
  if (lane == 0) g[o] = acc + ldf(gb, o, flag);
}

// ---- tail stage 2: layernorm over [g | d] -> lnv (1 block, tiny traffic) ----
__global__ void k_ln(const float* __restrict__ g, const float* __restrict__ d,
                     const void* lng, const void* lnb, float* __restrict__ lnv,
                     const int* flagp) {
  __shared__ float red[256];
  __shared__ float stats[2];
  int flag = flagp[0];
  int t = threadIdx.x;
  float v0 = g[t], v1 = d[t];
  red[t] = v0 + v1; __syncthreads();
  for (int s = 128; s > 0; s >>= 1) { if (t < s) red[t] += red[t + s]; __syncthreads(); }
  if (t == 0) stats[0] = red[0];
  __syncthreads();
  red[t] = v0 * v0 + v1 * v1; __syncthreads();
  for (int s = 128; s > 0; s >>= 1) { if (t < s) red[t] += red[t + s]; __syncthreads(); }
  if (t == 0) stats[1] = red[0];
  __syncthreads();
  float mu = stats[0] * (1.f / 512.f);
  float var = stats[1] * (1.f / 512.f) - mu * mu;
  float istd = rsqrtf(var + 1e-5f);
  lnv[t]       = (v0 - mu) * istd * ldf(lng, t, flag)       + ldf(lnb, t, flag);
  lnv[t + 256] = (v1 - mu) * istd * ldf(lng, t + 256, flag) + ldf(lnb, t + 256, flag);
}

// ---- tail stage 3: h1 = relu(lnv @ fusion_w.T + fb) (64 blocks, uint4 row loads) ----
__global__ void k_fuse(const float* __restrict__ lnv, const void* fw, const void* fb,
                       float* __restrict__ h1, const int* flagp) {
  __shared__ float lv[512];
  int flag = flagp[0];
  int t = threadIdx.x, w = t >> 6, lane = t & 63;
  lv[t] = lnv[t]; lv[t + 256] = lnv[t + 256];
  __syncthreads();
  int o = blockIdx.x * 4 + w;      // 0..255
  float acc = 0.f;
  if (flag) {
    uint4 u = *((const uint4*)((const unsigned short*)fw + o * 512) + lane);  // 8 bf16
    const float* l = &lv[lane * 8];
    acc = bfu(u.x & 0xffff) * l[0] + bfu(u.x >> 16) * l[1]
        + bfu(u.y & 0xffff) * l[2] + bfu(u.y >> 16) * l[3]
        + bfu(u.z & 0xffff) * l[4] + bfu(u.z >> 16) * l[5]
        + bfu(u.w & 0xffff) * l[6] + bfu(u.w >> 16) * l[7];
  } else {
    const float4* fv = (const float4*)((const float*)fw + o * 512);
    float4 a = fv[lane * 2], b = fv[lane * 2 + 1];
    const float* l = &lv[lane * 8];
    acc = a.x * l[0] + a.y * l[1] + a.z * l[2] + a.w * l[3]
        + b.x * l[4] + b.y * l[5] + b.z * l[6] + b.w * l[7];
  }
  acc = wsum(acc);
  if (lane == 0) h1[o] = fmaxf(acc + ldf(fb, o, flag), 0.0f);
}

// ---- tail stage 4: task + time heads (5 blocks) ----
__global__ void k_out(const float* __restrict__ h1, const void* tw, const void* tb,
                      const void* tmw, const void* tmb, void* out, const int* flagp) {
  int flag = flagp[0];
  int t = threadIdx.x, w = t >> 6, lane = t & 63;
  int o = blockIdx.x * 4 + w;
  if (o >= 17) return;
  float acc = 0.f;
  if (o < 16) { for (int k = lane; k < 256; k += 64) acc += h1[k] * ldf(tw, o * 256 + k, flag); }
  else        { for (int k = lane; k < 256; k += 64) acc += h1[k] * ldf(tmw, k, flag); }
  acc = wsum(acc);
  if (lane == 0) {
    float bias = (o < 16) ? ldf(tb, o, flag) : ldf(tmb, 0, flag);
    stf(out, o, acc + bias, flag);
  }
}

extern "C" void kernel_launch(void* const* d_in, const int* in_sizes, int n_in,
                              void* d_out, int out_size, void* d_ws, size_t ws_size,
                              hipStream_t stream) {
  const void* x    = d_in[0];
  const int*  ei   = (const int*)d_in[1];
  const void* docf = d_in[2];
  const void* pw   = d_in[3];
  const void* h0   = d_in[4];
  const void* wih  = d_in[5];
  const void* whh  = d_in[6];
  const void* bih  = d_in[7];
  const void* bhh  = d_in[8];
  const void* gw   = d_in[9];
  const void* gb   = d_in[10];
  const void* dw   = d_in[11];
  const void* db   = d_in[12];
  const void* lng  = d_in[13];
  const void* lnb  = d_in[14];
  const void* fw   = d_in[15];
  const void* fb   = d_in[16];
  const void* tw   = d_in[17];
  const void* tb   = d_in[18];
  const void* tmw  = d_in[19];
  const void* tmb  = d_in[20];

  const int* row = ei;
  const int* col = ei + EE;

  float* wsf = (float*)d_ws;
  int*   wsi = (int*)d_ws;

  hipMemsetAsync(wsi + P_HIST, 0, (size_t)ZERO_LEN * 4, stream);
  k_detect<<<1, 256, 0, stream>>>((const unsigned short*)x, wsi + P_FLAG);
  k_hcol<<<NB * CC, HTH, 0, stream>>>(col, wsi + P_PART);
  k_redA<<<NDBLK + 64, 256, 0, stream>>>(wsi + P_PART, wsf + P_DIS, docf, dw, db,
                                         wsf + P_D, wsi + P_FLAG);
  k_hrow<<<NB * CC, HTH, 0, stream>>>(row, col, wsf + P_DIS, wsf + P_PART);
  k_redB<<<NDBLK, 256, 0, stream>>>(wsf + P_PART, wsf + P_DIS, wsf + P_C);
  k_x<<<XBLOCKS, 256, 0, stream>>>(x, pw, wsf + P_C, wsf + P_SCORE,
                                   wsi + P_HIST, wsf + P_S8, wsi + P_FLAG);
  k_thresh<<<1, 256, 0, stream>>>(wsi + P_HIST, wsi + P_THR, wsf + P_S8, wsf + P_SV);
  k_collect<<<NDBLK, 256, 0, stream>>>(wsf + P_SCORE, wsi + P_THR, wsi + P_CANDN,
                                       (unsigned*)(wsi + P_CKEY), wsi + P_CIDX);
  k_top<<<1, 256, 0, stream>>>(wsi + P_CANDN, (const unsigned*)(wsi + P_CKEY),
                               wsi + P_CIDX, x, wsf + P_XT, wsi + P_FLAG);
  k_gru<<<16, 256, 0, stream>>>(wsf + P_XT, h0, wih, whh, bih, bhh, wsf + P_WW, wsi + P_FLAG);
  k_g<<<64, 256, 0, stream>>>(wsf + P_SV, wsf + P_WW, gw, gb, wsf + P_G, wsi + P_FLAG);
  k_ln<<<1, 256, 0, stream>>>(wsf + P_G, wsf + P_D, lng, lnb, wsf + P_LNV, wsi + P_FLAG);
  k_fuse<<<64, 256, 0, stream>>>(wsf + P_LNV, fw, fb, wsf + P_H1, wsi + P_FLAG);
  k_out<<<5, 256, 0, stream>>>(wsf + P_H1, tw, tb, tmw, tmb, d_out, wsi + P_FLAG);
}

// Round 2
// 407.410 us; speedup vs baseline: 1.2386x; 1.0383x over previous
//
#include <hip/hip_runtime.h>
#include <hip/hip_bf16.h>

#define NN    200000
#define EE    3200000
#define DDIMC 768

#define NB    25        // node buckets
#define BSH   13
#define BSZ   8192      // nodes per bucket -> 32KB LDS histogram
#define CC    12        // edge chunks per bucket
#define NI4   800000    // EE/4 int4s
#define BW4   2048      // int4 window (32KB)
#define HTH   1024      // histogram block threads
#define PARTW (NB * CC * BSZ)

#define NDBLK 782       // ceil(NN/256)
#define XBLOCKS 1024
#define CAPL  4096

// ---- workspace layout (word offsets) ----
#define P_PART  0
#define P_HIST  PARTW                    // 65536 i32 (zeroed)
#define P_CANDN (P_HIST + 65536)         // 8 (zeroed)
#define P_S8    (P_CANDN + 8)            // 512 (zeroed)
#define ZERO_LEN (65536 + 8 + 512)       // from P_HIST
#define P_FLAG  (P_S8 + 512)
#define P_THR   (P_FLAG + 8)
#define P_SV    (P_THR + 8)
#define P_D     (P_SV + 64)
#define P_DIS   (P_D + 256)
#define P_C     (P_DIS + NN)
#define P_SCORE (P_C + NN)
#define P_CKEY  (P_SCORE + NN)
#define P_CIDX  (P_CKEY + 4096)
#define P_XT    (P_CIDX + 4096)
#define P_WW    (P_XT + 4096)
#define P_G     (P_WW + 4096)            // 256 f32
#define P_LNV   (P_G + 256)              // 512 f32
#define P_H1    (P_LNV + 512)            // 256 f32

// ---- helpers (proven) ----
__device__ __forceinline__ float ldf(const void* p, int i, int bf) {
  if (bf) return __bfloat162float(((const __hip_bfloat16*)p)[i]);
  return ((const float*)p)[i];
}
__device__ __forceinline__ void stf(void* p, int i, float v, int bf) {
  if (bf) ((__hip_bfloat16*)p)[i] = __float2bfloat16(v);
  else ((float*)p)[i] = v;
}
__device__ __forceinline__ float bfu(unsigned u) {   // low 16 bits -> bf16 value
  return __uint_as_float(u << 16);
}
__device__ __forceinline__ float wsum(float v) {
#pragma unroll
  for (int m = 32; m >= 1; m >>= 1) v += __shfl_xor(v, m, 64);
  return v;
}
__device__ __forceinline__ int wsumi(int v) {
#pragma unroll
  for (int m = 32; m >= 1; m >>= 1) v += __shfl_xor(v, m, 64);
  return v;
}
__device__ __forceinline__ unsigned sortkey(float f) {
  unsigned u = __float_as_uint(f);
  return (u & 0x80000000u) ? ~u : (u | 0x80000000u);
}

// ---- dtype detector (proven) ----
__global__ void k_detect(const unsigned short* x16, int* flag) {
  __shared__ int cnt;
  if (threadIdx.x == 0) cnt = 0;
  __syncthreads();
  int ok = 0;
  for (int k = threadIdx.x; k < 512; k += 256) {
    unsigned short u = x16[2 * k];
    int e = (u >> 7) & 0xFF;
    if (u == 0 || (e >= 100 && e <= 150)) ok++;
  }
  atomicAdd(&cnt, ok);
  __syncthreads();
  if (threadIdx.x == 0) flag[0] = (cnt >= 400) ? 1 : 0;
}

// ---- bucketed degree histogram (proven) ----
__global__ void __launch_bounds__(HTH) k_hcol(const int* __restrict__ col, int* __restrict__ part) {
  __shared__ int lh[BSZ];
  int t = threadIdx.x;
  int b = blockIdx.x / CC, j = blockIdx.x % CC;
  for (int k = t; k < BSZ; k += HTH) lh[k] = 0;
  __syncthreads();
  int base = b << BSH;
  const int4* c4 = (const int4*)col;
  for (int w0 = j * BW4; w0 < NI4; w0 += CC * BW4) {
    int end = w0 + BW4; if (end > NI4) end = NI4;
    for (int i = w0 + t; i < end; i += HTH) {
      int4 v = c4[i];
      int a0 = v.x - base, a1 = v.y - base, a2 = v.z - base, a3 = v.w - base;
      if ((unsigned)a0 < (unsigned)BSZ) atomicAdd(&lh[a0], 1);
      if ((unsigned)a1 < (unsigned)BSZ) atomicAdd(&lh[a1], 1);
      if ((unsigned)a2 < (unsigned)BSZ) atomicAdd(&lh[a2], 1);
      if ((unsigned)a3 < (unsigned)BSZ) atomicAdd(&lh[a3], 1);
    }
  }
  __syncthreads();
  int* dst = part + (size_t)blockIdx.x * BSZ;
  for (int k = t; k < BSZ; k += HTH) dst[k] = lh[k];
}

// ---- reduce degree partials -> dis; doc matvec on extra blocks (proven) ----
__global__ void k_redA(const int* __restrict__ part, float* __restrict__ dis,
                       const void* docf, const void* dw, const void* db,
                       float* __restrict__ d, const int* flagp) {
  if (blockIdx.x < NDBLK) {
    int i = blockIdx.x * 256 + threadIdx.x;
    if (i < NN) {
      int b = i >> BSH, k = i & (BSZ - 1);
      const int* p = part + (size_t)b * CC * BSZ + k;
      int deg = 1;
#pragma unroll
      for (int j = 0; j < CC; j++) deg += p[(size_t)j * BSZ];
      dis[i] = rsqrtf((float)deg);
    }
  } else {
    int flag = flagp[0];
    int o = (blockIdx.x - NDBLK) * 4 + (threadIdx.x >> 6);
    int lane = threadIdx.x & 63;
    float acc = 0.f;
    for (int k = lane; k < DDIMC; k += 64) acc += ldf(docf, k, flag) * ldf(dw, o * DDIMC + k, flag);
    acc = wsum(acc);
    if (lane == 0) d[o] = fmaxf(acc + ldf(db, o, flag), 0.0f);
  }
}

// ---- weighted bucket histogram over row, weight = dis[col] (proven) ----
__global__ void __launch_bounds__(HTH) k_hrow(const int* __restrict__ row, const int* __restrict__ col,
                                              const float* __restrict__ dis, float* __restrict__ part) {
  __shared__ float lh[BSZ];
  int t = threadIdx.x;
  int b = blockIdx.x / CC, j = blockIdx.x % CC;
  for (int k = t; k < BSZ; k += HTH) lh[k] = 0.f;
  __syncthreads();
  int base = b << BSH;
  const int4* r4 = (const int4*)row;
  const int4* c4 = (const int4*)col;
  for (int w0 = j * BW4; w0 < NI4; w0 += CC * BW4) {
    int end = w0 + BW4; if (end > NI4) end = NI4;
    for (int i = w0 + t; i < end; i += HTH) {
      int4 r = r4[i];
      int4 c = c4[i];
      int a0 = r.x - base, a1 = r.y - base, a2 = r.z - base, a3 = r.w - base;
      if ((unsigned)a0 < (unsigned)BSZ) atomicAdd(&lh[a0], dis[c.x]);
      if ((unsigned)a1 < (unsigned)BSZ) atomicAdd(&lh[a1], dis[c.y]);
      if ((unsigned)a2 < (unsigned)BSZ) atomicAdd(&lh[a2], dis[c.z]);
      if ((unsigned)a3 < (unsigned)BSZ) atomicAdd(&lh[a3], dis[c.w]);
    }
  }
  __syncthreads();
  float* dst = part + (size_t)blockIdx.x * BSZ;
  for (int k = t; k < BSZ; k += HTH) dst[k] = lh[k];
}

// ---- reduce weighted partials -> c_i = dis_i*tacc_i + dis_i^2 (proven) ----
__global__ void k_redB(const float* __restrict__ part, const float* __restrict__ dis,
                       float* __restrict__ c) {
  int i = blockIdx.x * 256 + threadIdx.x;
  if (i < NN) {
    int b = i >> BSH, k = i & (BSZ - 1);
    const float* p = part + (size_t)b * CC * BSZ + k;
    float s = 0.f;
#pragma unroll
    for (int j = 0; j < CC; j++) s += p[(size_t)j * BSZ];
    float dv = dis[i];
    c[i] = dv * s + dv * dv;
  }
}

// ---- fused x pass (REWORKED): 16B/lane vector loads, multi-row per wave ----
// Old: 1 row/wave-iter, scalar 2B bf16 loads, 6-step shfl chain + atomic per
// row -> latency-serialized (VALUBusy 7%, HBM 4.8%, 97us). New: each lane
// loads uint4 (8 bf16) -> 8 rows/wave-iter (f32: float4, 4 rows/iter), dot
// reduce is 3 shfl steps within 8-lane row group, column accumulator reduced
// once at kernel end instead of per-row.
__global__ void k_x(const void* x, const void* pw, const float* __restrict__ c,
                    float* __restrict__ score, int* __restrict__ hist,
                    float* __restrict__ s8, const int* flagp) {
  __shared__ float sred[4][64];
  int flag = flagp[0];
  int t = threadIdx.x;
  int lane = t & 63;
  int w = t >> 6;
  int wid = (blockIdx.x * 256 + t) >> 6;
  int nw = (gridDim.x * 256) >> 6;

  if (flag) {
    // ---- bf16 path: 8 rows per wave-iteration, 8 lanes per row ----
    int g  = lane >> 3;        // row subgroup 0..7
    int c0 = (lane & 7) * 8;   // column base for this lane
    float pwv[8];
#pragma unroll
    for (int j = 0; j < 8; j++) pwv[j] = ldf(pw, c0 + j, 1);
    float s = 0.f;
#pragma unroll
    for (int j = 0; j < 8; j++) s += pwv[j] * pwv[j];
    float inv = 1.0f / sqrtf(wsum(s) * 0.125f);   // each column counted 8x
    float sacc[8] = {0.f, 0.f, 0.f, 0.f, 0.f, 0.f, 0.f, 0.f};
    const uint4* x4 = (const uint4*)x;
    for (int r0 = wid * 8; r0 < NN; r0 += nw * 8) {   // NN % 8 == 0
      int r = r0 + g;
      uint4 u = x4[r * 8 + (lane & 7)];               // contiguous 1KiB/wave
      float xv[8] = { bfu(u.x & 0xffff), bfu(u.x >> 16),
                      bfu(u.y & 0xffff), bfu(u.y >> 16),
                      bfu(u.z & 0xffff), bfu(u.z >> 16),
                      bfu(u.w & 0xffff), bfu(u.w >> 16) };
      float dot = 0.f;
#pragma unroll
      for (int j = 0; j < 8; j++) dot += xv[j] * pwv[j];
      dot += __shfl_xor(dot, 1, 64);
      dot += __shfl_xor(dot, 2, 64);
      dot += __shfl_xor(dot, 4, 64);
      float cr = c[r];
#pragma unroll
      for (int j = 0; j < 8; j++) sacc[j] += cr * xv[j];
      if ((lane & 7) == 0) {
        float sc = dot * inv;
        score[r] = sc;
        atomicAdd(&hist[sortkey(sc) >> 16], 1);
      }
    }
#pragma unroll
    for (int j = 0; j < 8; j++) {
      sacc[j] += __shfl_xor(sacc[j], 8, 64);
      sacc[j] += __shfl_xor(sacc[j], 16, 64);
      sacc[j] += __shfl_xor(sacc[j], 32, 64);
    }
    if (lane < 8) {
#pragma unroll
      for (int j = 0; j < 8; j++) sred[w][lane * 8 + j] = sacc[j];
    }
  } else {
    // ---- f32 path: 4 rows per wave-iteration, 16 lanes per row ----
    int g  = lane >> 4;        // row subgroup 0..3
    int c0 = (lane & 15) * 4;  // column base
    float pwv[4];
#pragma unroll
    for (int j = 0; j < 4; j++) pwv[j] = ((const float*)pw)[c0 + j];
    float s = 0.f;
#pragma unroll
    for (int j = 0; j < 4; j++) s += pwv[j] * pwv[j];
    float inv = 1.0f / sqrtf(wsum(s) * (1.f / 16.f));  // each column counted 16x
    float sacc[4] = {0.f, 0.f, 0.f, 0.f};
    const float4* x4 = (const float4*)x;
    for (int r0 = wid * 4; r0 < NN; r0 += nw * 4) {    // NN % 4 == 0
      int r = r0 + g;
      float4 v = x4[r * 16 + (lane & 15)];             // contiguous 1KiB/wave
      float xv[4] = { v.x, v.y, v.z, v.w };
      float dot = 0.f;
#pragma unroll
      for (int j = 0; j < 4; j++) dot += xv[j] * pwv[j];
      dot += __shfl_xor(dot, 1, 64);
      dot += __shfl_xor(dot, 2, 64);
      dot += __shfl_xor(dot, 4, 64);
      dot += __shfl_xor(dot, 8, 64);
      float cr = c[r];
#pragma unroll
      for (int j = 0; j < 4; j++) sacc[j] += cr * xv[j];
      if ((lane & 15) == 0) {
        float sc = dot * inv;
        score[r] = sc;
        atomicAdd(&hist[sortkey(sc) >> 16], 1);
      }
    }
#pragma unroll
    for (int j = 0; j < 4; j++) {
      sacc[j] += __shfl_xor(sacc[j], 16, 64);
      sacc[j] += __shfl_xor(sacc[j], 32, 64);
    }
    if (lane < 16) {
#pragma unroll
      for (int j = 0; j < 4; j++) sred[w][lane * 4 + j] = sacc[j];
    }
  }
  __syncthreads();
  if (w == 0)
    atomicAdd(&s8[(blockIdx.x & 7) * 64 + lane],
              sred[0][lane] + sred[1][lane] + sred[2][lane] + sred[3][lane]);
}

// ---- threshold (proven) ----
__global__ void k_thresh(const int* __restrict__ hist, int* __restrict__ thrB,
                         const float* __restrict__ s8, float* __restrict__ svec) {
  __shared__ int part[256];
  __shared__ int segl[256];
  __shared__ int res2[2];
  int t = threadIdx.x, w = t >> 6, lane = t & 63;
  if (t < 64) {
    float a = 0.f;
    for (int r = 0; r < 8; r++) a += s8[r * 64 + t];
    svec[t] = a;
  }
  for (int m = w; m < 256; m += 4) {
    const int* hb = &hist[m * 256];
    int a = hb[lane] + hb[lane + 64] + hb[lane + 128] + hb[lane + 192];
    a = wsumi(a);
    if (lane == 0) part[m] = a;
  }
  __syncthreads();
  if (t == 0) {
    int acc = 0, seg = 0, above = 0;
    for (int b = 255; b >= 0; b--) {
      if (acc + part[b] >= 64) { seg = b; above = acc; break; }
      acc += part[b];
    }
    res2[0] = seg; res2[1] = above;
  }
  __syncthreads();
  segl[t] = hist[res2[0] * 256 + t];
  __syncthreads();
  if (t == 0) {
    int acc = res2[1], B = res2[0] * 256;
    for (int j = 255; j >= 0; j--) {
      acc += segl[j];
      if (acc >= 64) { B = res2[0] * 256 + j; break; }
    }
    thrB[0] = B;
  }
}

// ---- collect (proven) ----
__global__ void k_collect(const float* __restrict__ score, const int* __restrict__ thrB,
                          int* __restrict__ candn, unsigned* __restrict__ ckey,
                          int* __restrict__ cidx) {
  int i = blockIdx.x * blockDim.x + threadIdx.x;
  if (i >= NN) return;
  unsigned u = sortkey(score[i]);
  if ((int)(u >> 16) >= thrB[0]) {
    int p = atomicAdd(candn, 1);
    if (p < CAPL) { ckey[p] = u; cidx[p] = i; }
  }
}

// ---- top-64 (proven) ----
__global__ void k_top(const int* __restrict__ candn, const unsigned* __restrict__ ckey,
                      const int* __restrict__ cidx, const void* x,
                      float* __restrict__ xt, const int* flagp) {
  __shared__ unsigned long long keys[CAPL];
  __shared__ int perm[64];
  __shared__ float ts[64];
  int flag = flagp[0];
  int t = threadIdx.x;
  int M = candn[0];
  if (M > CAPL) M = CAPL;
  for (int j = t; j < M; j += 256)
    keys[j] = (((unsigned long long)ckey[j]) << 32) |
              (unsigned long long)(0xFFFFFFFFu - (unsigned)cidx[j]);
  __syncthreads();
  for (int j = t; j < M; j += 256) {
    unsigned long long k = keys[j];
    int rank = 0;
    for (int i = 0; i < M; i++) rank += (keys[i] > k) ? 1 : 0;
    if (rank < 64) {
      unsigned ku = (unsigned)(k >> 32);
      unsigned idx = 0xFFFFFFFFu - (unsigned)(k & 0xFFFFFFFFu);
      perm[rank] = (int)idx;
      unsigned bits = (ku & 0x80000000u) ? (ku ^ 0x80000000u) : ~ku;
      ts[rank] = tanhf(__uint_as_float(bits));
    }
  }
  __syncthreads();
  for (int q = t; q < 4096; q += 256) {
    int j = q >> 6, f = q & 63;
    xt[q] = ldf(x, perm[j] * 64 + f, flag) * ts[j];
  }
}

// ---- GRU (proven round-0 rework): coalesced staging, LDS-side transpose ----
#define GS 193
__device__ __forceinline__ void stage_w(const void* src, float* dst, int flag, int t) {
  if (flag) {
    const uint4* s4 = (const uint4*)src;          // 12288 bf16 = 1536 uint4
    for (int k = t; k < 1536; k += 256) {
      uint4 u = s4[k];
      int e = k << 3; int o = e >> 6, f = e & 63; // 8 elems share o, f..f+7
      float* d = &dst[f * GS + o];
      d[0]      = bfu(u.x & 0xffff); d[GS]     = bfu(u.x >> 16);
      d[2 * GS] = bfu(u.y & 0xffff); d[3 * GS] = bfu(u.y >> 16);
      d[4 * GS] = bfu(u.z & 0xffff); d[5 * GS] = bfu(u.z >> 16);
      d[6 * GS] = bfu(u.w & 0xffff); d[7 * GS] = bfu(u.w >> 16);
    }
  } else {
    const float4* s4 = (const float4*)src;        // 12288 f32 = 3072 float4
    for (int k = t; k < 3072; k += 256) {
      float4 v = s4[k];
      int e = k << 2; int o = e >> 6, f = e & 63; // 4 elems share o, f..f+3
      float* d = &dst[f * GS + o];
      d[0] = v.x; d[GS] = v.y; d[2 * GS] = v.z; d[3 * GS] = v.w;
    }
  }
}

__global__ void k_gru(const float* __restrict__ xt, const void* h0g, const void* wihg,
                      const void* whhg, const void* bihg, const void* bhhg,
                      float* __restrict__ Wout, const int* flagp) {
  __shared__ float wb1[64 * GS];   // wih^T  [f][o], 49.4KB
  __shared__ float wb2[64 * GS];   // whh^T  [f][o], 49.4KB
  __shared__ float xtr[256];
  __shared__ float h0r[256];
  int flag = flagp[0];
  int t = threadIdx.x;
  int j0 = blockIdx.x * 4;
  { int jj = t >> 6, f = t & 63;
    xtr[t] = xt[(j0 + jj) * 64 + f];
    h0r[t] = ldf(h0g, (j0 + jj) * 64 + f, flag); }
  stage_w(wihg, wb1, flag, t);
  stage_w(whhg, wb2, flag, t);
  __syncthreads();
  int jl = t >> 6, c2 = t & 63;
  float xr = 0, xz = 0, xn = 0, hr = 0, hz = 0, hn = 0;
#pragma unroll 4
  for (int f = 0; f < 64; f++) {
    float xv = xtr[jl * 64 + f];
    float hv = h0r[jl * 64 + f];
    const float* w1 = &wb1[f * GS];
    const float* w2 = &wb2[f * GS];
    xr += xv * w1[c2]; xz += xv * w1[64 + c2]; xn += xv * w1[128 + c2];
    hr += hv * w2[c2]; hz += hv * w2[64 + c2]; hn += hv * w2[128 + c2];
  }
  xr += ldf(bihg, c2, flag); xz += ldf(bihg, 64 + c2, flag); xn += ldf(bihg, 128 + c2, flag);
  hr += ldf(bhhg, c2, flag); hz += ldf(bhhg, 64 + c2, flag); hn += ldf(bhhg, 128 + c2, flag);
  float rg = 1.f / (1.f + expf(-(xr + hr)));
  float zg = 1.f / (1.f + expf(-(xz + hz)));
  float nc = tanhf(xn + rg * hn);
  Wout[(j0 + jl) * 64 + c2] = (1.f - zg) * nc + zg * h0r[jl * 64 + c2];
}

// ---- tail stage 1: g[o] = pooled @ gnn_fc_w.T + gnn_fc_b  (64 blocks) ----
__global__ void k_g(const float* __restrict__ svec, const float* __restrict__ Wm,
                    const void* gw, const void* gb, float* __restrict__ g,
                    const int* flagp) {
  __shared__ float pooled[64];
  int flag = flagp[0];
  int t = threadIdx.x, w = t >> 6, lane = t & 63;
  if (t < 64) {
    float a = 0.f;
    for (int f = 0; f < 64; f++) a += svec[f] * Wm[f * 64 + t];
    pooled[t] = a * (1.0f / (float)NN);
  }
  __syncthreads();
  int o = blockIdx.x * 4 + w;      // 0..255
  float acc = pooled[lane] * ldf(gw, o * 64 + lane, flag);
  acc = wsum(acc);
  if (lane == 0) g[o] = acc + ldf(gb, o, flag);
}

// ---- tail stage 2: layernorm over [g | d] -> lnv (1 block, tiny traffic) ----
__global__ void k_ln(const float* __restrict__ g, const float* __restrict__ d,
                     const void* lng, const void* lnb, float* __restrict__ lnv,
                     const int* flagp) {
  __shared__ float red[256];
  __shared__ float stats[2];
  int flag = flagp[0];
  int t = threadIdx.x;
  float v0 = g[t], v1 = d[t];
  red[t] = v0 + v1; __syncthreads();
  for (int s = 128; s > 0; s >>= 1) { if (t < s) red[t] += red[t + s]; __syncthreads(); }
  if (t == 0) stats[0] = red[0];
  __syncthreads();
  red[t] = v0 * v0 + v1 * v1; __syncthreads();
  for (int s = 128; s > 0; s >>= 1) { if (t < s) red[t] += red[t + s]; __syncthreads(); }
  if (t == 0) stats[1] = red[0];
  __syncthreads();
  float mu = stats[0] * (1.f / 512.f);
  float var = stats[1] * (1.f / 512.f) - mu * mu;
  float istd = rsqrtf(var + 1e-5f);
  lnv[t]       = (v0 - mu) * istd * ldf(lng, t, flag)       + ldf(lnb, t, flag);
  lnv[t + 256] = (v1 - mu) * istd * ldf(lng, t + 256, flag) + ldf(lnb, t + 256, flag);
}

// ---- tail stage 3: h1 = relu(lnv @ fusion_w.T + fb) (64 blocks, uint4 row loads) ----
__global__ void k_fuse(const float* __restrict__ lnv, const void* fw, const void* fb,
                       float* __restrict__ h1, const int* flagp) {
  __shared__ float lv[512];
  int flag = flagp[0];
  int t = threadIdx.x, w = t >> 6, lane = t & 63;
  lv[t] = lnv[t]; lv[t + 256] = lnv[t + 256];
  __syncthreads();
  int o = blockIdx.x * 4 + w;      // 0..255
  float acc = 0.f;
  if (flag) {
    uint4 u = *((const uint4*)((const unsigned short*)fw + o * 512) + lane);  // 8 bf16
    const float* l = &lv[lane * 8];
    acc = bfu(u.x & 0xffff) * l[0] + bfu(u.x >> 16) * l[1]
        + bfu(u.y & 0xffff) * l[2] + bfu(u.y >> 16) * l[3]
        + bfu(u.z & 0xffff) * l[4] + bfu(u.z >> 16) * l[5]
        + bfu(u.w & 0xffff) * l[6] + bfu(u.w >> 16) * l[7];
  } else {
    const float4* fv = (const float4*)((const float*)fw + o * 512);
    float4 a = fv[lane * 2], b = fv[lane * 2 + 1];
    const float* l = &lv[lane * 8];
    acc = a.x * l[0] + a.y * l[1] + a.z * l[2] + a.w * l[3]
        + b.x * l[4] + b.y * l[5] + b.z * l[6] + b.w * l[7];
  }
  acc = wsum(acc);
  if (lane == 0) h1[o] = fmaxf(acc + ldf(fb, o, flag), 0.0f);
}

// ---- tail stage 4: task + time heads (5 blocks) ----
__global__ void k_out(const float* __restrict__ h1, const void* tw, const void* tb,
                      const void* tmw, const void* tmb, void* out, const int* flagp) {
  int flag = flagp[0];
  int t = threadIdx.x, w = t >> 6, lane = t & 63;
  int o = blockIdx.x * 4 + w;
  if (o >= 17) return;
  float acc = 0.f;
  if (o < 16) { for (int k = lane; k < 256; k += 64) acc += h1[k] * ldf(tw, o * 256 + k, flag); }
  else        { for (int k = lane; k < 256; k += 64) acc += h1[k] * ldf(tmw, k, flag); }
  acc = wsum(acc);
  if (lane == 0) {
    float bias = (o < 16) ? ldf(tb, o, flag) : ldf(tmb, 0, flag);
    stf(out, o, acc + bias, flag);
  }
}

extern "C" void kernel_launch(void* const* d_in, const int* in_sizes, int n_in,
                              void* d_out, int out_size, void* d_ws, size_t ws_size,
                              hipStream_t stream) {
  const void* x    = d_in[0];
  const int*  ei   = (const int*)d_in[1];
  const void* docf = d_in[2];
  const void* pw   = d_in[3];
  const void* h0   = d_in[4];
  const void* wih  = d_in[5];
  const void* whh  = d_in[6];
  const void* bih  = d_in[7];
  const void* bhh  = d_in[8];
  const void* gw   = d_in[9];
  const void* gb   = d_in[10];
  const void* dw   = d_in[11];
  const void* db   = d_in[12];
  const void* lng  = d_in[13];
  const void* lnb  = d_in[14];
  const void* fw   = d_in[15];
  const void* fb   = d_in[16];
  const void* tw   = d_in[17];
  const void* tb   = d_in[18];
  const void* tmw  = d_in[19];
  const void* tmb  = d_in[20];

  const int* row = ei;
  const int* col = ei + EE;

  float* wsf = (float*)d_ws;
  int*   wsi = (int*)d_ws;

  hipMemsetAsync(wsi + P_HIST, 0, (size_t)ZERO_LEN * 4, stream);
  k_detect<<<1, 256, 0, stream>>>((const unsigned short*)x, wsi + P_FLAG);
  k_hcol<<<NB * CC, HTH, 0, stream>>>(col, wsi + P_PART);
  k_redA<<<NDBLK + 64, 256, 0, stream>>>(wsi + P_PART, wsf + P_DIS, docf, dw, db,
                                         wsf + P_D, wsi + P_FLAG);
  k_hrow<<<NB * CC, HTH, 0, stream>>>(row, col, wsf + P_DIS, wsf + P_PART);
  k_redB<<<NDBLK, 256, 0, stream>>>(wsf + P_PART, wsf + P_DIS, wsf + P_C);
  k_x<<<XBLOCKS, 256, 0, stream>>>(x, pw, wsf + P_C, wsf + P_SCORE,
                                   wsi + P_HIST, wsf + P_S8, wsi + P_FLAG);
  k_thresh<<<1, 256, 0, stream>>>(wsi + P_HIST, wsi + P_THR, wsf + P_S8, wsf + P_SV);
  k_collect<<<NDBLK, 256, 0, stream>>>(wsf + P_SCORE, wsi + P_THR, wsi + P_CANDN,
                                       (unsigned*)(wsi + P_CKEY), wsi + P_CIDX);
  k_top<<<1, 256, 0, stream>>>(wsi + P_CANDN, (const unsigned*)(wsi + P_CKEY),
                               wsi + P_CIDX, x, wsf + P_XT, wsi + P_FLAG);
  k_gru<<<16, 256, 0, stream>>>(wsf + P_XT, h0, wih, whh, bih, bhh, wsf + P_WW, wsi + P_FLAG);
  k_g<<<64, 256, 0, stream>>>(wsf + P_SV, wsf + P_WW, gw, gb, wsf + P_G, wsi + P_FLAG);
  k_ln<<<1, 256, 0, stream>>>(wsf + P_G, wsf + P_D, lng, lnb, wsf + P_LNV, wsi + P_FLAG);
  k_fuse<<<64, 256, 0, stream>>>(wsf + P_LNV, fw, fb, wsf + P_H1, wsi + P_FLAG);
  k_out<<<5, 256, 0, stream>>>(wsf + P_H1, tw, tb, tmw, tmb, d_out, wsi + P_FLAG);
}

// Round 3
// 353.651 us; speedup vs baseline: 1.4268x; 1.1520x over previous
//
#include <hip/hip_runtime.h>
#include <hip/hip_bf16.h>

#define NN    200000
#define EE    3200000
#define DDIMC 768

#define NB    25        // node buckets
#define BSH   13
#define BSZ   8192      // nodes per bucket -> 32KB LDS histogram
#define CC    12        // edge chunks per bucket
#define NI4   800000    // EE/4 int4s
#define BW4   2048      // int4 window (32KB)
#define HTH   1024      // histogram block threads
#define PARTW (NB * CC * BSZ)

#define NDBLK 782       // ceil(NN/256)
#define XBLOCKS 1024
#define CAPL  4096

#define HB    64        // score-hist partial blocks (NN/HB = 3125 exact)
#define HW    32768     // packed u32 words (2x16-bit counts) = 65536 buckets

// ---- workspace layout (word offsets) ----
#define P_PART  0                        // also reused for k_hist partials (HB*HW = 2.10M <= 2.46M)
#define P_HIST  PARTW                    // 65536 i32 (fully overwritten by k_redH)
#define P_CANDN (P_HIST + 65536)         // 8 (zeroed)
#define P_S8    (P_CANDN + 8)            // 512 (zeroed)
#define ZERO_LEN (8 + 512)               // from P_CANDN (hist no longer needs zeroing)
#define P_FLAG  (P_S8 + 512)
#define P_THR   (P_FLAG + 8)
#define P_SV    (P_THR + 8)
#define P_D     (P_SV + 64)
#define P_DIS   (P_D + 256)
#define P_C     (P_DIS + NN)
#define P_SCORE (P_C + NN)
#define P_CKEY  (P_SCORE + NN)
#define P_CIDX  (P_CKEY + 4096)
#define P_XT    (P_CIDX + 4096)
#define P_WW    (P_XT + 4096)
#define P_G     (P_WW + 4096)            // 256 f32
#define P_LNV   (P_G + 256)              // 512 f32
#define P_H1    (P_LNV + 512)            // 256 f32

// ---- helpers (proven) ----
__device__ __forceinline__ float ldf(const void* p, int i, int bf) {
  if (bf) return __bfloat162float(((const __hip_bfloat16*)p)[i]);
  return ((const float*)p)[i];
}
__device__ __forceinline__ void stf(void* p, int i, float v, int bf) {
  if (bf) ((__hip_bfloat16*)p)[i] = __float2bfloat16(v);
  else ((float*)p)[i] = v;
}
__device__ __forceinline__ float bfu(unsigned u) {   // low 16 bits -> bf16 value
  return __uint_as_float(u << 16);
}
__device__ __forceinline__ float wsum(float v) {
#pragma unroll
  for (int m = 32; m >= 1; m >>= 1) v += __shfl_xor(v, m, 64);
  return v;
}
__device__ __forceinline__ int wsumi(int v) {
#pragma unroll
  for (int m = 32; m >= 1; m >>= 1) v += __shfl_xor(v, m, 64);
  return v;
}
__device__ __forceinline__ unsigned sortkey(float f) {
  unsigned u = __float_as_uint(f);
  return (u & 0x80000000u) ? ~u : (u | 0x80000000u);
}

// ---- dtype detector (proven) ----
__global__ void k_detect(const unsigned short* x16, int* flag) {
  __shared__ int cnt;
  if (threadIdx.x == 0) cnt = 0;
  __syncthreads();
  int ok = 0;
  for (int k = threadIdx.x; k < 512; k += 256) {
    unsigned short u = x16[2 * k];
    int e = (u >> 7) & 0xFF;
    if (u == 0 || (e >= 100 && e <= 150)) ok++;
  }
  atomicAdd(&cnt, ok);
  __syncthreads();
  if (threadIdx.x == 0) flag[0] = (cnt >= 400) ? 1 : 0;
}

// ---- bucketed degree histogram (proven) ----
__global__ void __launch_bounds__(HTH) k_hcol(const int* __restrict__ col, int* __restrict__ part) {
  __shared__ int lh[BSZ];
  int t = threadIdx.x;
  int b = blockIdx.x / CC, j = blockIdx.x % CC;
  for (int k = t; k < BSZ; k += HTH) lh[k] = 0;
  __syncthreads();
  int base = b << BSH;
  const int4* c4 = (const int4*)col;
  for (int w0 = j * BW4; w0 < NI4; w0 += CC * BW4) {
    int end = w0 + BW4; if (end > NI4) end = NI4;
    for (int i = w0 + t; i < end; i += HTH) {
      int4 v = c4[i];
      int a0 = v.x - base, a1 = v.y - base, a2 = v.z - base, a3 = v.w - base;
      if ((unsigned)a0 < (unsigned)BSZ) atomicAdd(&lh[a0], 1);
      if ((unsigned)a1 < (unsigned)BSZ) atomicAdd(&lh[a1], 1);
      if ((unsigned)a2 < (unsigned)BSZ) atomicAdd(&lh[a2], 1);
      if ((unsigned)a3 < (unsigned)BSZ) atomicAdd(&lh[a3], 1);
    }
  }
  __syncthreads();
  int* dst = part + (size_t)blockIdx.x * BSZ;
  for (int k = t; k < BSZ; k += HTH) dst[k] = lh[k];
}

// ---- reduce degree partials -> dis; doc matvec on extra blocks (proven) ----
__global__ void k_redA(const int* __restrict__ part, float* __restrict__ dis,
                       const void* docf, const void* dw, const void* db,
                       float* __restrict__ d, const int* flagp) {
  if (blockIdx.x < NDBLK) {
    int i = blockIdx.x * 256 + threadIdx.x;
    if (i < NN) {
      int b = i >> BSH, k = i & (BSZ - 1);
      const int* p = part + (size_t)b * CC * BSZ + k;
      int deg = 1;
#pragma unroll
      for (int j = 0; j < CC; j++) deg += p[(size_t)j * BSZ];
      dis[i] = rsqrtf((float)deg);
    }
  } else {
    int flag = flagp[0];
    int o = (blockIdx.x - NDBLK) * 4 + (threadIdx.x >> 6);
    int lane = threadIdx.x & 63;
    float acc = 0.f;
    for (int k = lane; k < DDIMC; k += 64) acc += ldf(docf, k, flag) * ldf(dw, o * DDIMC + k, flag);
    acc = wsum(acc);
    if (lane == 0) d[o] = fmaxf(acc + ldf(db, o, flag), 0.0f);
  }
}

// ---- weighted bucket histogram over row, weight = dis[col] (proven) ----
__global__ void __launch_bounds__(HTH) k_hrow(const int* __restrict__ row, const int* __restrict__ col,
                                              const float* __restrict__ dis, float* __restrict__ part) {
  __shared__ float lh[BSZ];
  int t = threadIdx.x;
  int b = blockIdx.x / CC, j = blockIdx.x % CC;
  for (int k = t; k < BSZ; k += HTH) lh[k] = 0.f;
  __syncthreads();
  int base = b << BSH;
  const int4* r4 = (const int4*)row;
  const int4* c4 = (const int4*)col;
  for (int w0 = j * BW4; w0 < NI4; w0 += CC * BW4) {
    int end = w0 + BW4; if (end > NI4) end = NI4;
    for (int i = w0 + t; i < end; i += HTH) {
      int4 r = r4[i];
      int4 c = c4[i];
      int a0 = r.x - base, a1 = r.y - base, a2 = r.z - base, a3 = r.w - base;
      if ((unsigned)a0 < (unsigned)BSZ) atomicAdd(&lh[a0], dis[c.x]);
      if ((unsigned)a1 < (unsigned)BSZ) atomicAdd(&lh[a1], dis[c.y]);
      if ((unsigned)a2 < (unsigned)BSZ) atomicAdd(&lh[a2], dis[c.z]);
      if ((unsigned)a3 < (unsigned)BSZ) atomicAdd(&lh[a3], dis[c.w]);
    }
  }
  __syncthreads();
  float* dst = part + (size_t)blockIdx.x * BSZ;
  for (int k = t; k < BSZ; k += HTH) dst[k] = lh[k];
}

// ---- reduce weighted partials -> c_i = dis_i*tacc_i + dis_i^2 (proven) ----
__global__ void k_redB(const float* __restrict__ part, const float* __restrict__ dis,
                       float* __restrict__ c) {
  int i = blockIdx.x * 256 + threadIdx.x;
  if (i < NN) {
    int b = i >> BSH, k = i & (BSZ - 1);
    const float* p = part + (size_t)b * CC * BSZ + k;
    float s = 0.f;
#pragma unroll
    for (int j = 0; j < CC; j++) s += p[(size_t)j * BSZ];
    float dv = dis[i];
    c[i] = dv * s + dv * dv;
  }
}

// ---- fused x pass (R2 rework): NO global hist atomics (they were ~90us of
// contended same-line device-scope atomics whose vmcnt-drain at the barrier
// serialized the kernel). Now: pure stream, score store + column accumulator. ----
__global__ void k_x(const void* x, const void* pw, const float* __restrict__ c,
                    float* __restrict__ score,
                    float* __restrict__ s8, const int* flagp) {
  __shared__ float sred[4][64];
  int flag = flagp[0];
  int t = threadIdx.x;
  int lane = t & 63;
  int w = t >> 6;
  int wid = (blockIdx.x * 256 + t) >> 6;
  int nw = (gridDim.x * 256) >> 6;

  if (flag) {
    // ---- bf16 path: 8 rows per wave-iteration, 8 lanes per row ----
    int g  = lane >> 3;        // row subgroup 0..7
    int c0 = (lane & 7) * 8;   // column base for this lane
    float pwv[8];
#pragma unroll
    for (int j = 0; j < 8; j++) pwv[j] = ldf(pw, c0 + j, 1);
    float s = 0.f;
#pragma unroll
    for (int j = 0; j < 8; j++) s += pwv[j] * pwv[j];
    float inv = 1.0f / sqrtf(wsum(s) * 0.125f);   // each column counted 8x
    float sacc[8] = {0.f, 0.f, 0.f, 0.f, 0.f, 0.f, 0.f, 0.f};
    const uint4* x4 = (const uint4*)x;
    for (int r0 = wid * 8; r0 < NN; r0 += nw * 8) {   // NN % 8 == 0
      int r = r0 + g;
      uint4 u = x4[r * 8 + (lane & 7)];               // contiguous 1KiB/wave
      float xv[8] = { bfu(u.x & 0xffff), bfu(u.x >> 16),
                      bfu(u.y & 0xffff), bfu(u.y >> 16),
                      bfu(u.z & 0xffff), bfu(u.z >> 16),
                      bfu(u.w & 0xffff), bfu(u.w >> 16) };
      float dot = 0.f;
#pragma unroll
      for (int j = 0; j < 8; j++) dot += xv[j] * pwv[j];
      dot += __shfl_xor(dot, 1, 64);
      dot += __shfl_xor(dot, 2, 64);
      dot += __shfl_xor(dot, 4, 64);
      float cr = c[r];
#pragma unroll
      for (int j = 0; j < 8; j++) sacc[j] += cr * xv[j];
      if ((lane & 7) == 0) score[r] = dot * inv;
    }
#pragma unroll
    for (int j = 0; j < 8; j++) {
      sacc[j] += __shfl_xor(sacc[j], 8, 64);
      sacc[j] += __shfl_xor(sacc[j], 16, 64);
      sacc[j] += __shfl_xor(sacc[j], 32, 64);
    }
    if (lane < 8) {
#pragma unroll
      for (int j = 0; j < 8; j++) sred[w][lane * 8 + j] = sacc[j];
    }
  } else {
    // ---- f32 path: 4 rows per wave-iteration, 16 lanes per row ----
    int g  = lane >> 4;        // row subgroup 0..3
    int c0 = (lane & 15) * 4;  // column base
    float pwv[4];
#pragma unroll
    for (int j = 0; j < 4; j++) pwv[j] = ((const float*)pw)[c0 + j];
    float s = 0.f;
#pragma unroll
    for (int j = 0; j < 4; j++) s += pwv[j] * pwv[j];
    float inv = 1.0f / sqrtf(wsum(s) * (1.f / 16.f));  // each column counted 16x
    float sacc[4] = {0.f, 0.f, 0.f, 0.f};
    const float4* x4 = (const float4*)x;
    for (int r0 = wid * 4; r0 < NN; r0 += nw * 4) {    // NN % 4 == 0
      int r = r0 + g;
      float4 v = x4[r * 16 + (lane & 15)];             // contiguous 1KiB/wave
      float xv[4] = { v.x, v.y, v.z, v.w };
      float dot = 0.f;
#pragma unroll
      for (int j = 0; j < 4; j++) dot += xv[j] * pwv[j];
      dot += __shfl_xor(dot, 1, 64);
      dot += __shfl_xor(dot, 2, 64);
      dot += __shfl_xor(dot, 4, 64);
      dot += __shfl_xor(dot, 8, 64);
      float cr = c[r];
#pragma unroll
      for (int j = 0; j < 4; j++) sacc[j] += cr * xv[j];
      if ((lane & 15) == 0) score[r] = dot * inv;
    }
#pragma unroll
    for (int j = 0; j < 4; j++) {
      sacc[j] += __shfl_xor(sacc[j], 16, 64);
      sacc[j] += __shfl_xor(sacc[j], 32, 64);
    }
    if (lane < 16) {
#pragma unroll
      for (int j = 0; j < 4; j++) sred[w][lane * 4 + j] = sacc[j];
    }
  }
  __syncthreads();
  if (w == 0)
    atomicAdd(&s8[(blockIdx.x & 7) * 64 + lane],
              sred[0][lane] + sred[1][lane] + sred[2][lane] + sred[3][lane]);
}

// ---- NEW: LDS-privatized full-resolution score histogram ----
// 65536 buckets packed 2x16-bit per u32 (128KB LDS). Per-block rows = 3125 <
// 2^16 so no carry crossing. Partials written coalesced into P_PART (dead by
// now). Replaces 200000 contended device-scope atomics with LDS atomics.
__global__ void __launch_bounds__(1024) k_hist(const float* __restrict__ score,
                                               unsigned* __restrict__ part) {
  __shared__ unsigned lh[HW];
  int t = threadIdx.x;
  for (int k = t; k < HW; k += 1024) lh[k] = 0u;
  __syncthreads();
  int r0 = blockIdx.x * (NN / HB);
  int r1 = r0 + (NN / HB);
  for (int i = r0 + t; i < r1; i += 1024) {
    unsigned b = sortkey(score[i]) >> 16;
    atomicAdd(&lh[b >> 1], 1u << ((b & 1) * 16));
  }
  __syncthreads();
  unsigned* dst = part + (size_t)blockIdx.x * HW;
  for (int k = t; k < HW; k += 1024) dst[k] = lh[k];
}

// ---- NEW: sum HB packed partials -> hist (fully overwrites, no memset need) ----
__global__ void k_redH(const unsigned* __restrict__ part, int* __restrict__ hist) {
  int w = blockIdx.x * 256 + threadIdx.x;   // 0..HW-1, grid 128 blocks
  unsigned lo = 0, hi = 0;
  for (int b = 0; b < HB; b++) {
    unsigned v = part[(size_t)b * HW + w];
    lo += v & 0xffffu;
    hi += v >> 16;
  }
  hist[2 * w]     = (int)lo;
  hist[2 * w + 1] = (int)hi;
}

// ---- threshold (proven) ----
__global__ void k_thresh(const int* __restrict__ hist, int* __restrict__ thrB,
                         const float* __restrict__ s8, float* __restrict__ svec) {
  __shared__ int part[256];
  __shared__ int segl[256];
  __shared__ int res2[2];
  int t = threadIdx.x, w = t >> 6, lane = t & 63;
  if (t < 64) {
    float a = 0.f;
    for (int r = 0; r < 8; r++) a += s8[r * 64 + t];
    svec[t] = a;
  }
  for (int m = w; m < 256; m += 4) {
    const int* hb = &hist[m * 256];
    int a = hb[lane] + hb[lane + 64] + hb[lane + 128] + hb[lane + 192];
    a = wsumi(a);
    if (lane == 0) part[m] = a;
  }
  __syncthreads();
  if (t == 0) {
    int acc = 0, seg = 0, above = 0;
    for (int b = 255; b >= 0; b--) {
      if (acc + part[b] >= 64) { seg = b; above = acc; break; }
      acc += part[b];
    }
    res2[0] = seg; res2[1] = above;
  }
  __syncthreads();
  segl[t] = hist[res2[0] * 256 + t];
  __syncthreads();
  if (t == 0) {
    int acc = res2[1], B = res2[0] * 256;
    for (int j = 255; j >= 0; j--) {
      acc += segl[j];
      if (acc >= 64) { B = res2[0] * 256 + j; break; }
    }
    thrB[0] = B;
  }
}

// ---- collect (proven) ----
__global__ void k_collect(const float* __restrict__ score, const int* __restrict__ thrB,
                          int* __restrict__ candn, unsigned* __restrict__ ckey,
                          int* __restrict__ cidx) {
  int i = blockIdx.x * blockDim.x + threadIdx.x;
  if (i >= NN) return;
  unsigned u = sortkey(score[i]);
  if ((int)(u >> 16) >= thrB[0]) {
    int p = atomicAdd(candn, 1);
    if (p < CAPL) { ckey[p] = u; cidx[p] = i; }
  }
}

// ---- top-64 (proven) ----
__global__ void k_top(const int* __restrict__ candn, const unsigned* __restrict__ ckey,
                      const int* __restrict__ cidx, const void* x,
                      float* __restrict__ xt, const int* flagp) {
  __shared__ unsigned long long keys[CAPL];
  __shared__ int perm[64];
  __shared__ float ts[64];
  int flag = flagp[0];
  int t = threadIdx.x;
  int M = candn[0];
  if (M > CAPL) M = CAPL;
  for (int j = t; j < M; j += 256)
    keys[j] = (((unsigned long long)ckey[j]) << 32) |
              (unsigned long long)(0xFFFFFFFFu - (unsigned)cidx[j]);
  __syncthreads();
  for (int j = t; j < M; j += 256) {
    unsigned long long k = keys[j];
    int rank = 0;
    for (int i = 0; i < M; i++) rank += (keys[i] > k) ? 1 : 0;
    if (rank < 64) {
      unsigned ku = (unsigned)(k >> 32);
      unsigned idx = 0xFFFFFFFFu - (unsigned)(k & 0xFFFFFFFFu);
      perm[rank] = (int)idx;
      unsigned bits = (ku & 0x80000000u) ? (ku ^ 0x80000000u) : ~ku;
      ts[rank] = tanhf(__uint_as_float(bits));
    }
  }
  __syncthreads();
  for (int q = t; q < 4096; q += 256) {
    int j = q >> 6, f = q & 63;
    xt[q] = ldf(x, perm[j] * 64 + f, flag) * ts[j];
  }
}

// ---- GRU (proven round-0 rework): coalesced staging, LDS-side transpose ----
#define GS 193
__device__ __forceinline__ void stage_w(const void* src, float* dst, int flag, int t) {
  if (flag) {
    const uint4* s4 = (const uint4*)src;          // 12288 bf16 = 1536 uint4
    for (int k = t; k < 1536; k += 256) {
      uint4 u = s4[k];
      int e = k << 3; int o = e >> 6, f = e & 63; // 8 elems share o, f..f+7
      float* d = &dst[f * GS + o];
      d[0]      = bfu(u.x & 0xffff); d[GS]     = bfu(u.x >> 16);
      d[2 * GS] = bfu(u.y & 0xffff); d[3 * GS] = bfu(u.y >> 16);
      d[4 * GS] = bfu(u.z & 0xffff); d[5 * GS] = bfu(u.z >> 16);
      d[6 * GS] = bfu(u.w & 0xffff); d[7 * GS] = bfu(u.w >> 16);
    }
  } else {
    const float4* s4 = (const float4*)src;        // 12288 f32 = 3072 float4
    for (int k = t; k < 3072; k += 256) {
      float4 v = s4[k];
      int e = k << 2; int o = e >> 6, f = e & 63; // 4 elems share o, f..f+3
      float* d = &dst[f * GS + o];
      d[0] = v.x; d[GS] = v.y; d[2 * GS] = v.z; d[3 * GS] = v.w;
    }
  }
}

__global__ void k_gru(const float* __restrict__ xt, const void* h0g, const void* wihg,
                      const void* whhg, const void* bihg, const void* bhhg,
                      float* __restrict__ Wout, const int* flagp) {
  __shared__ float wb1[64 * GS];   // wih^T  [f][o], 49.4KB
  __shared__ float wb2[64 * GS];   // whh^T  [f][o], 49.4KB
  __shared__ float xtr[256];
  __shared__ float h0r[256];
  int flag = flagp[0];
  int t = threadIdx.x;
  int j0 = blockIdx.x * 4;
  { int jj = t >> 6, f = t & 63;
    xtr[t] = xt[(j0 + jj) * 64 + f];
    h0r[t] = ldf(h0g, (j0 + jj) * 64 + f, flag); }
  stage_w(wihg, wb1, flag, t);
  stage_w(whhg, wb2, flag, t);
  __syncthreads();
  int jl = t >> 6, c2 = t & 63;
  float xr = 0, xz = 0, xn = 0, hr = 0, hz = 0, hn = 0;
#pragma unroll 4
  for (int f = 0; f < 64; f++) {
    float xv = xtr[jl * 64 + f];
    float hv = h0r[jl * 64 + f];
    const float* w1 = &wb1[f * GS];
    const float* w2 = &wb2[f * GS];
    xr += xv * w1[c2]; xz += xv * w1[64 + c2]; xn += xv * w1[128 + c2];
    hr += hv * w2[c2]; hz += hv * w2[64 + c2]; hn += hv * w2[128 + c2];
  }
  xr += ldf(bihg, c2, flag); xz += ldf(bihg, 64 + c2, flag); xn += ldf(bihg, 128 + c2, flag);
  hr += ldf(bhhg, c2, flag); hz += ldf(bhhg, 64 + c2, flag); hn += ldf(bhhg, 128 + c2, flag);
  float rg = 1.f / (1.f + expf(-(xr + hr)));
  float zg = 1.f / (1.f + expf(-(xz + hz)));
  float nc = tanhf(xn + rg * hn);
  Wout[(j0 + jl) * 64 + c2] = (1.f - zg) * nc + zg * h0r[jl * 64 + c2];
}

// ---- tail stage 1: g[o] = pooled @ gnn_fc_w.T + gnn_fc_b  (64 blocks) ----
__global__ void k_g(const float* __restrict__ svec, const float* __restrict__ Wm,
                    const void* gw, const void* gb, float* __restrict__ g,
                    const int* flagp) {
  __shared__ float pooled[64];
  int flag = flagp[0];
  int t = threadIdx.x, w = t >> 6, lane = t & 63;
  if (t < 64) {
    float a = 0.f;
    for (int f = 0; f < 64; f++) a += svec[f] * Wm[f * 64 + t];
    pooled[t] = a * (1.0f / (float)NN);
  }
  __syncthreads();
  int o = blockIdx.x * 4 + w;      // 0..255
  float acc = pooled[lane] * ldf(gw, o * 64 + lane, flag);
  acc = wsum(acc);
  if (lane == 0) g[o] = acc + ldf(gb, o, flag);
}

// ---- tail stage 2: layernorm over [g | d] -> lnv (1 block, tiny traffic) ----
__global__ void k_ln(const float* __restrict__ g, const float* __restrict__ d,
                     const void* lng, const void* lnb, float* __restrict__ lnv,
                     const int* flagp) {
  __shared__ float red[256];
  __shared__ float stats[2];
  int flag = flagp[0];
  int t = threadIdx.x;
  float v0 = g[t], v1 = d[t];
  red[t] = v0 + v1; __syncthreads();
  for (int s = 128; s > 0; s >>= 1) { if (t < s) red[t] += red[t + s]; __syncthreads(); }
  if (t == 0) stats[0] = red[0];
  __syncthreads();
  red[t] = v0 * v0 + v1 * v1; __syncthreads();
  for (int s = 128; s > 0; s >>= 1) { if (t < s) red[t] += red[t + s]; __syncthreads(); }
  if (t == 0) stats[1] = red[0];
  __syncthreads();
  float mu = stats[0] * (1.f / 512.f);
  float var = stats[1] * (1.f / 512.f) - mu * mu;
  float istd = rsqrtf(var + 1e-5f);
  lnv[t]       = (v0 - mu) * istd * ldf(lng, t, flag)       + ldf(lnb, t, flag);
  lnv[t + 256] = (v1 - mu) * istd * ldf(lng, t + 256, flag) + ldf(lnb, t + 256, flag);
}

// ---- tail stage 3: h1 = relu(lnv @ fusion_w.T + fb) (64 blocks, uint4 row loads) ----
__global__ void k_fuse(const float* __restrict__ lnv, const void* fw, const void* fb,
                       float* __restrict__ h1, const int* flagp) {
  __shared__ float lv[512];
  int flag = flagp[0];
  int t = threadIdx.x, w = t >> 6, lane = t & 63;
  lv[t] = lnv[t]; lv[t + 256] = lnv[t + 256];
  __syncthreads();
  int o = blockIdx.x * 4 + w;      // 0..255
  float acc = 0.f;
  if (flag) {
    uint4 u = *((const uint4*)((const unsigned short*)fw + o * 512) + lane);  // 8 bf16
    const float* l = &lv[lane * 8];
    acc = bfu(u.x & 0xffff) * l[0] + bfu(u.x >> 16) * l[1]
        + bfu(u.y & 0xffff) * l[2] + bfu(u.y >> 16) * l[3]
        + bfu(u.z & 0xffff) * l[4] + bfu(u.z >> 16) * l[5]
        + bfu(u.w & 0xffff) * l[6] + bfu(u.w >> 16) * l[7];
  } else {
    const float4* fv = (const float4*)((const float*)fw + o * 512);
    float4 a = fv[lane * 2], b = fv[lane * 2 + 1];
    const float* l = &lv[lane * 8];
    acc = a.x * l[0] + a.y * l[1] + a.z * l[2] + a.w * l[3]
        + b.x * l[4] + b.y * l[5] + b.z * l[6] + b.w * l[7];
  }
  acc = wsum(acc);
  if (lane == 0) h1[o] = fmaxf(acc + ldf(fb, o, flag), 0.0f);
}

// ---- tail stage 4: task + time heads (5 blocks) ----
__global__ void k_out(const float* __restrict__ h1, const void* tw, const void* tb,
                      const void* tmw, const void* tmb, void* out, const int* flagp) {
  int flag = flagp[0];
  int t = threadIdx.x, w = t >> 6, lane = t & 63;
  int o = blockIdx.x * 4 + w;
  if (o >= 17) return;
  float acc = 0.f;
  if (o < 16) { for (int k = lane; k < 256; k += 64) acc += h1[k] * ldf(tw, o * 256 + k, flag); }
  else        { for (int k = lane; k < 256; k += 64) acc += h1[k] * ldf(tmw, k, flag); }
  acc = wsum(acc);
  if (lane == 0) {
    float bias = (o < 16) ? ldf(tb, o, flag) : ldf(tmb, 0, flag);
    stf(out, o, acc + bias, flag);
  }
}

extern "C" void kernel_launch(void* const* d_in, const int* in_sizes, int n_in,
                              void* d_out, int out_size, void* d_ws, size_t ws_size,
                              hipStream_t stream) {
  const void* x    = d_in[0];
  const int*  ei   = (const int*)d_in[1];
  const void* docf = d_in[2];
  const void* pw   = d_in[3];
  const void* h0   = d_in[4];
  const void* wih  = d_in[5];
  const void* whh  = d_in[6];
  const void* bih  = d_in[7];
  const void* bhh  = d_in[8];
  const void* gw   = d_in[9];
  const void* gb   = d_in[10];
  const void* dw   = d_in[11];
  const void* db   = d_in[12];
  const void* lng  = d_in[13];
  const void* lnb  = d_in[14];
  const void* fw   = d_in[15];
  const void* fb   = d_in[16];
  const void* tw   = d_in[17];
  const void* tb   = d_in[18];
  const void* tmw  = d_in[19];
  const void* tmb  = d_in[20];

  const int* row = ei;
  const int* col = ei + EE;

  float* wsf = (float*)d_ws;
  int*   wsi = (int*)d_ws;

  hipMemsetAsync(wsi + P_CANDN, 0, (size_t)ZERO_LEN * 4, stream);
  k_detect<<<1, 256, 0, stream>>>((const unsigned short*)x, wsi + P_FLAG);
  k_hcol<<<NB * CC, HTH, 0, stream>>>(col, wsi + P_PART);
  k_redA<<<NDBLK + 64, 256, 0, stream>>>(wsi + P_PART, wsf + P_DIS, docf, dw, db,
                                         wsf + P_D, wsi + P_FLAG);
  k_hrow<<<NB * CC, HTH, 0, stream>>>(row, col, wsf + P_DIS, wsf + P_PART);
  k_redB<<<NDBLK, 256, 0, stream>>>(wsf + P_PART, wsf + P_DIS, wsf + P_C);
  k_x<<<XBLOCKS, 256, 0, stream>>>(x, pw, wsf + P_C, wsf + P_SCORE,
                                   wsf + P_S8, wsi + P_FLAG);
  k_hist<<<HB, 1024, 0, stream>>>(wsf + P_SCORE, (unsigned*)(wsi + P_PART));
  k_redH<<<HW / 256, 256, 0, stream>>>((const unsigned*)(wsi + P_PART), wsi + P_HIST);
  k_thresh<<<1, 256, 0, stream>>>(wsi + P_HIST, wsi + P_THR, wsf + P_S8, wsf + P_SV);
  k_collect<<<NDBLK, 256, 0, stream>>>(wsf + P_SCORE, wsi + P_THR, wsi + P_CANDN,
                                       (unsigned*)(wsi + P_CKEY), wsi + P_CIDX);
  k_top<<<1, 256, 0, stream>>>(wsi + P_CANDN, (const unsigned*)(wsi + P_CKEY),
                               wsi + P_CIDX, x, wsf + P_XT, wsi + P_FLAG);
  k_gru<<<16, 256, 0, stream>>>(wsf + P_XT, h0, wih, whh, bih, bhh, wsf + P_WW, wsi + P_FLAG);
  k_g<<<64, 256, 0, stream>>>(wsf + P_SV, wsf + P_WW, gw, gb, wsf + P_G, wsi + P_FLAG);
  k_ln<<<1, 256, 0, stream>>>(wsf + P_G, wsf + P_D, lng, lnb, wsf + P_LNV, wsi + P_FLAG);
  k_fuse<<<64, 256, 0, stream>>>(wsf + P_LNV, fw, fb, wsf + P_H1, wsi + P_FLAG);
  k_out<<<5, 256, 0, stream>>>(wsf + P_H1, tw, tb, tmw, tmb, d_out, wsi + P_FLAG);
}

// Round 4
// 313.952 us; speedup vs baseline: 1.6073x; 1.1264x over previous
//
#include <hip/hip_runtime.h>
#include <hip/hip_bf16.h>

#define NN    200000
#define EE    3200000
#define DDIMC 768

#define NI4   800000    // EE/4 int4s
#define BW4   2048      // int4 window (32KB)
#define HTH   1024      // histogram block threads
#define PARTW (25 * 12 * 8192)   // legacy region size (k_hist partials live here)

// hcol: packed 2x16-bit counts, 32768 nodes / 64KB LDS, 7 passes
#define BSZC  32768
#define BSHC  15
#define NBC   7
#define CCC   24
// hrow: float, 16384 nodes / 64KB LDS, 13 passes
#define BSZR  16384
#define BSHR  14
#define NBR   13
#define CCR   24

#define NDBLK 782       // ceil(NN/256)
#define XBLOCKS 1024
#define CAPL  4096

#define HB    64        // score-hist partial blocks (NN/HB = 3125 exact)
#define HW    32768     // packed u32 words (2x16-bit counts) = 65536 buckets

// ---- workspace layout (word offsets) ----
#define P_PART  0                        // k_hist partials (HB*HW = 2.10M <= 2.46M)
#define P_DEGM  P_PART                   // merged packed degree, NBC*BSZC/2 = 114688 u32
#define P_PARTM (P_DEGM + 114688)        // merged row partials, NBR*BSZR = 212992 f32
#define PZERO_LEN 327680                 // degm + partm zeroing
#define P_HIST  PARTW                    // 65536 i32 (fully overwritten by k_redH)
#define P_CANDN (P_HIST + 65536)         // 8 (zeroed)
#define P_S8    (P_CANDN + 8)            // 512 (zeroed)
#define ZERO_LEN (8 + 512)               // from P_CANDN
#define P_FLAG  (P_S8 + 512)
#define P_THR   (P_FLAG + 8)
#define P_SV    (P_THR + 8)
#define P_D     (P_SV + 64)
#define P_DIS   (P_D + 256)
#define P_C     (P_DIS + NN)
#define P_SCORE (P_C + NN)
#define P_CKEY  (P_SCORE + NN)
#define P_CIDX  (P_CKEY + 4096)
#define P_XT    (P_CIDX + 4096)
#define P_WW    (P_XT + 4096)
#define P_G     (P_WW + 4096)            // 256 f32
#define P_LNV   (P_G + 256)              // 512 f32
#define P_H1    (P_LNV + 512)            // 256 f32

// ---- helpers (proven) ----
__device__ __forceinline__ float ldf(const void* p, int i, int bf) {
  if (bf) return __bfloat162float(((const __hip_bfloat16*)p)[i]);
  return ((const float*)p)[i];
}
__device__ __forceinline__ void stf(void* p, int i, float v, int bf) {
  if (bf) ((__hip_bfloat16*)p)[i] = __float2bfloat16(v);
  else ((float*)p)[i] = v;
}
__device__ __forceinline__ float bfu(unsigned u) {   // low 16 bits -> bf16 value
  return __uint_as_float(u << 16);
}
__device__ __forceinline__ float wsum(float v) {
#pragma unroll
  for (int m = 32; m >= 1; m >>= 1) v += __shfl_xor(v, m, 64);
  return v;
}
__device__ __forceinline__ int wsumi(int v) {
#pragma unroll
  for (int m = 32; m >= 1; m >>= 1) v += __shfl_xor(v, m, 64);
  return v;
}
__device__ __forceinline__ unsigned sortkey(float f) {
  unsigned u = __float_as_uint(f);
  return (u & 0x80000000u) ? ~u : (u | 0x80000000u);
}

// ---- dtype detector (proven) ----
__global__ void k_detect(const unsigned short* x16, int* flag) {
  __shared__ int cnt;
  if (threadIdx.x == 0) cnt = 0;
  __syncthreads();
  int ok = 0;
  for (int k = threadIdx.x; k < 512; k += 256) {
    unsigned short u = x16[2 * k];
    int e = (u >> 7) & 0xFF;
    if (u == 0 || (e >= 100 && e <= 150)) ok++;
  }
  atomicAdd(&cnt, ok);
  __syncthreads();
  if (threadIdx.x == 0) flag[0] = (cnt >= 400) ? 1 : 0;
}

// ---- degree histogram (R3 rework): 32K-node buckets packed 2xu16 in 64KB LDS,
// 7 passes instead of 25, CC=24 halves per-thread iterations, coalesced
// atomic merge into flat node-indexed degm (no per-chunk partials). ----
__global__ void __launch_bounds__(HTH) k_hcol(const int* __restrict__ col,
                                              unsigned* __restrict__ degm) {
  __shared__ unsigned lh[BSZC / 2];
  int t = threadIdx.x;
  int b = blockIdx.x / CCC, j = blockIdx.x % CCC;
  for (int k = t; k < BSZC / 2; k += HTH) lh[k] = 0u;
  __syncthreads();
  int base = b << BSHC;
  const int4* c4 = (const int4*)col;
  for (int w0 = j * BW4; w0 < NI4; w0 += CCC * BW4) {
    int end = w0 + BW4; if (end > NI4) end = NI4;
    for (int i = w0 + t; i < end; i += HTH) {
      int4 v = c4[i];
      int a0 = v.x - base, a1 = v.y - base, a2 = v.z - base, a3 = v.w - base;
      if ((unsigned)a0 < (unsigned)BSZC) atomicAdd(&lh[a0 >> 1], 1u << ((a0 & 1) * 16));
      if ((unsigned)a1 < (unsigned)BSZC) atomicAdd(&lh[a1 >> 1], 1u << ((a1 & 1) * 16));
      if ((unsigned)a2 < (unsigned)BSZC) atomicAdd(&lh[a2 >> 1], 1u << ((a2 & 1) * 16));
      if ((unsigned)a3 < (unsigned)BSZC) atomicAdd(&lh[a3 >> 1], 1u << ((a3 & 1) * 16));
    }
  }
  __syncthreads();
  // packed merge: per-node totals < 2^16, carries can't cross halves
  unsigned* dst = degm + (size_t)b * (BSZC / 2);
  for (int k = t; k < BSZC / 2; k += HTH) {
    unsigned v = lh[k];
    if (v) atomicAdd(&dst[k], v);
  }
}

// ---- reduce: dis from packed degm; doc matvec on extra blocks ----
__global__ void k_redA(const unsigned* __restrict__ degm, float* __restrict__ dis,
                       const void* docf, const void* dw, const void* db,
                       float* __restrict__ d, const int* flagp) {
  if (blockIdx.x < NDBLK) {
    int i = blockIdx.x * 256 + threadIdx.x;
    if (i < NN) {
      unsigned w_ = degm[i >> 1];
      int deg = 1 + (int)((w_ >> ((i & 1) * 16)) & 0xffffu);
      dis[i] = rsqrtf((float)deg);
    }
  } else {
    int flag = flagp[0];
    int o = (blockIdx.x - NDBLK) * 4 + (threadIdx.x >> 6);
    int lane = threadIdx.x & 63;
    float acc = 0.f;
    for (int k = lane; k < DDIMC; k += 64) acc += ldf(docf, k, flag) * ldf(dw, o * DDIMC + k, flag);
    acc = wsum(acc);
    if (lane == 0) d[o] = fmaxf(acc + ldf(db, o, flag), 0.0f);
  }
}

// ---- weighted row histogram (R3 rework): 16K-node float buckets in 64KB LDS,
// 13 passes instead of 25, CC=24, coalesced atomic merge into flat partm. ----
__global__ void __launch_bounds__(HTH) k_hrow(const int* __restrict__ row, const int* __restrict__ col,
                                              const float* __restrict__ dis,
                                              float* __restrict__ partm) {
  __shared__ float lh[BSZR];
  int t = threadIdx.x;
  int b = blockIdx.x / CCR, j = blockIdx.x % CCR;
  for (int k = t; k < BSZR; k += HTH) lh[k] = 0.f;
  __syncthreads();
  int base = b << BSHR;
  const int4* r4 = (const int4*)row;
  const int4* c4 = (const int4*)col;
  for (int w0 = j * BW4; w0 < NI4; w0 += CCR * BW4) {
    int end = w0 + BW4; if (end > NI4) end = NI4;
    for (int i = w0 + t; i < end; i += HTH) {
      int4 r = r4[i];
      int4 c = c4[i];
      int a0 = r.x - base, a1 = r.y - base, a2 = r.z - base, a3 = r.w - base;
      if ((unsigned)a0 < (unsigned)BSZR) atomicAdd(&lh[a0], dis[c.x]);
      if ((unsigned)a1 < (unsigned)BSZR) atomicAdd(&lh[a1], dis[c.y]);
      if ((unsigned)a2 < (unsigned)BSZR) atomicAdd(&lh[a2], dis[c.z]);
      if ((unsigned)a3 < (unsigned)BSZR) atomicAdd(&lh[a3], dis[c.w]);
    }
  }
  __syncthreads();
  float* dst = partm + (size_t)b * BSZR;
  for (int k = t; k < BSZR; k += HTH) {
    float v = lh[k];
    if (v != 0.f) atomicAdd(&dst[k], v);
  }
}

// ---- reduce: c_i = dis_i*partm_i + dis_i^2 (flat node-indexed) ----
__global__ void k_redB(const float* __restrict__ partm, const float* __restrict__ dis,
                       float* __restrict__ c) {
  int i = blockIdx.x * 256 + threadIdx.x;
  if (i < NN) {
    float dv = dis[i];
    c[i] = dv * partm[i] + dv * dv;
  }
}

// ---- fused x pass (proven R2): pure stream, score + column accumulator ----
__global__ void k_x(const void* x, const void* pw, const float* __restrict__ c,
                    float* __restrict__ score,
                    float* __restrict__ s8, const int* flagp) {
  __shared__ float sred[4][64];
  int flag = flagp[0];
  int t = threadIdx.x;
  int lane = t & 63;
  int w = t >> 6;
  int wid = (blockIdx.x * 256 + t) >> 6;
  int nw = (gridDim.x * 256) >> 6;

  if (flag) {
    int g  = lane >> 3;        // row subgroup 0..7
    int c0 = (lane & 7) * 8;   // column base for this lane
    float pwv[8];
#pragma unroll
    for (int j = 0; j < 8; j++) pwv[j] = ldf(pw, c0 + j, 1);
    float s = 0.f;
#pragma unroll
    for (int j = 0; j < 8; j++) s += pwv[j] * pwv[j];
    float inv = 1.0f / sqrtf(wsum(s) * 0.125f);   // each column counted 8x
    float sacc[8] = {0.f, 0.f, 0.f, 0.f, 0.f, 0.f, 0.f, 0.f};
    const uint4* x4 = (const uint4*)x;
    for (int r0 = wid * 8; r0 < NN; r0 += nw * 8) {   // NN % 8 == 0
      int r = r0 + g;
      uint4 u = x4[r * 8 + (lane & 7)];               // contiguous 1KiB/wave
      float xv[8] = { bfu(u.x & 0xffff), bfu(u.x >> 16),
                      bfu(u.y & 0xffff), bfu(u.y >> 16),
                      bfu(u.z & 0xffff), bfu(u.z >> 16),
                      bfu(u.w & 0xffff), bfu(u.w >> 16) };
      float dot = 0.f;
#pragma unroll
      for (int j = 0; j < 8; j++) dot += xv[j] * pwv[j];
      dot += __shfl_xor(dot, 1, 64);
      dot += __shfl_xor(dot, 2, 64);
      dot += __shfl_xor(dot, 4, 64);
      float cr = c[r];
#pragma unroll
      for (int j = 0; j < 8; j++) sacc[j] += cr * xv[j];
      if ((lane & 7) == 0) score[r] = dot * inv;
    }
#pragma unroll
    for (int j = 0; j < 8; j++) {
      sacc[j] += __shfl_xor(sacc[j], 8, 64);
      sacc[j] += __shfl_xor(sacc[j], 16, 64);
      sacc[j] += __shfl_xor(sacc[j], 32, 64);
    }
    if (lane < 8) {
#pragma unroll
      for (int j = 0; j < 8; j++) sred[w][lane * 8 + j] = sacc[j];
    }
  } else {
    int g  = lane >> 4;        // row subgroup 0..3
    int c0 = (lane & 15) * 4;  // column base
    float pwv[4];
#pragma unroll
    for (int j = 0; j < 4; j++) pwv[j] = ((const float*)pw)[c0 + j];
    float s = 0.f;
#pragma unroll
    for (int j = 0; j < 4; j++) s += pwv[j] * pwv[j];
    float inv = 1.0f / sqrtf(wsum(s) * (1.f / 16.f));  // each column counted 16x
    float sacc[4] = {0.f, 0.f, 0.f, 0.f};
    const float4* x4 = (const float4*)x;
    for (int r0 = wid * 4; r0 < NN; r0 += nw * 4) {    // NN % 4 == 0
      int r = r0 + g;
      float4 v = x4[r * 16 + (lane & 15)];             // contiguous 1KiB/wave
      float xv[4] = { v.x, v.y, v.z, v.w };
      float dot = 0.f;
#pragma unroll
      for (int j = 0; j < 4; j++) dot += xv[j] * pwv[j];
      dot += __shfl_xor(dot, 1, 64);
      dot += __shfl_xor(dot, 2, 64);
      dot += __shfl_xor(dot, 4, 64);
      dot += __shfl_xor(dot, 8, 64);
      float cr = c[r];
#pragma unroll
      for (int j = 0; j < 4; j++) sacc[j] += cr * xv[j];
      if ((lane & 15) == 0) score[r] = dot * inv;
    }
#pragma unroll
    for (int j = 0; j < 4; j++) {
      sacc[j] += __shfl_xor(sacc[j], 16, 64);
      sacc[j] += __shfl_xor(sacc[j], 32, 64);
    }
    if (lane < 16) {
#pragma unroll
      for (int j = 0; j < 4; j++) sred[w][lane * 4 + j] = sacc[j];
    }
  }
  __syncthreads();
  if (w == 0)
    atomicAdd(&s8[(blockIdx.x & 7) * 64 + lane],
              sred[0][lane] + sred[1][lane] + sred[2][lane] + sred[3][lane]);
}

// ---- LDS-privatized full-resolution score histogram (proven R2) ----
__global__ void __launch_bounds__(1024) k_hist(const float* __restrict__ score,
                                               unsigned* __restrict__ part) {
  __shared__ unsigned lh[HW];
  int t = threadIdx.x;
  for (int k = t; k < HW; k += 1024) lh[k] = 0u;
  __syncthreads();
  int r0 = blockIdx.x * (NN / HB);
  int r1 = r0 + (NN / HB);
  for (int i = r0 + t; i < r1; i += 1024) {
    unsigned b = sortkey(score[i]) >> 16;
    atomicAdd(&lh[b >> 1], 1u << ((b & 1) * 16));
  }
  __syncthreads();
  unsigned* dst = part + (size_t)blockIdx.x * HW;
  for (int k = t; k < HW; k += 1024) dst[k] = lh[k];
}

// ---- sum HB packed partials -> hist (proven R2) ----
__global__ void k_redH(const unsigned* __restrict__ part, int* __restrict__ hist) {
  int w = blockIdx.x * 256 + threadIdx.x;   // 0..HW-1, grid 128 blocks
  unsigned lo = 0, hi = 0;
  for (int b = 0; b < HB; b++) {
    unsigned v = part[(size_t)b * HW + w];
    lo += v & 0xffffu;
    hi += v >> 16;
  }
  hist[2 * w]     = (int)lo;
  hist[2 * w + 1] = (int)hi;
}

// ---- threshold (proven) ----
__global__ void k_thresh(const int* __restrict__ hist, int* __restrict__ thrB,
                         const float* __restrict__ s8, float* __restrict__ svec) {
  __shared__ int part[256];
  __shared__ int segl[256];
  __shared__ int res2[2];
  int t = threadIdx.x, w = t >> 6, lane = t & 63;
  if (t < 64) {
    float a = 0.f;
    for (int r = 0; r < 8; r++) a += s8[r * 64 + t];
    svec[t] = a;
  }
  for (int m = w; m < 256; m += 4) {
    const int* hb = &hist[m * 256];
    int a = hb[lane] + hb[lane + 64] + hb[lane + 128] + hb[lane + 192];
    a = wsumi(a);
    if (lane == 0) part[m] = a;
  }
  __syncthreads();
  if (t == 0) {
    int acc = 0, seg = 0, above = 0;
    for (int b = 255; b >= 0; b--) {
      if (acc + part[b] >= 64) { seg = b; above = acc; break; }
      acc += part[b];
    }
    res2[0] = seg; res2[1] = above;
  }
  __syncthreads();
  segl[t] = hist[res2[0] * 256 + t];
  __syncthreads();
  if (t == 0) {
    int acc = res2[1], B = res2[0] * 256;
    for (int j = 255; j >= 0; j--) {
      acc += segl[j];
      if (acc >= 64) { B = res2[0] * 256 + j; break; }
    }
    thrB[0] = B;
  }
}

// ---- collect (proven) ----
__global__ void k_collect(const float* __restrict__ score, const int* __restrict__ thrB,
                          int* __restrict__ candn, unsigned* __restrict__ ckey,
                          int* __restrict__ cidx) {
  int i = blockIdx.x * blockDim.x + threadIdx.x;
  if (i >= NN) return;
  unsigned u = sortkey(score[i]);
  if ((int)(u >> 16) >= thrB[0]) {
    int p = atomicAdd(candn, 1);
    if (p < CAPL) { ckey[p] = u; cidx[p] = i; }
  }
}

// ---- top-64 (proven) ----
__global__ void k_top(const int* __restrict__ candn, const unsigned* __restrict__ ckey,
                      const int* __restrict__ cidx, const void* x,
                      float* __restrict__ xt, const int* flagp) {
  __shared__ unsigned long long keys[CAPL];
  __shared__ int perm[64];
  __shared__ float ts[64];
  int flag = flagp[0];
  int t = threadIdx.x;
  int M = candn[0];
  if (M > CAPL) M = CAPL;
  for (int j = t; j < M; j += 256)
    keys[j] = (((unsigned long long)ckey[j]) << 32) |
              (unsigned long long)(0xFFFFFFFFu - (unsigned)cidx[j]);
  __syncthreads();
  for (int j = t; j < M; j += 256) {
    unsigned long long k = keys[j];
    int rank = 0;
    for (int i = 0; i < M; i++) rank += (keys[i] > k) ? 1 : 0;
    if (rank < 64) {
      unsigned ku = (unsigned)(k >> 32);
      unsigned idx = 0xFFFFFFFFu - (unsigned)(k & 0xFFFFFFFFu);
      perm[rank] = (int)idx;
      unsigned bits = (ku & 0x80000000u) ? (ku ^ 0x80000000u) : ~ku;
      ts[rank] = tanhf(__uint_as_float(bits));
    }
  }
  __syncthreads();
  for (int q = t; q < 4096; q += 256) {
    int j = q >> 6, f = q & 63;
    xt[q] = ldf(x, perm[j] * 64 + f, flag) * ts[j];
  }
}

// ---- GRU (proven round-0 rework): coalesced staging, LDS-side transpose ----
#define GS 193
__device__ __forceinline__ void stage_w(const void* src, float* dst, int flag, int t) {
  if (flag) {
    const uint4* s4 = (const uint4*)src;          // 12288 bf16 = 1536 uint4
    for (int k = t; k < 1536; k += 256) {
      uint4 u = s4[k];
      int e = k << 3; int o = e >> 6, f = e & 63; // 8 elems share o, f..f+7
      float* d = &dst[f * GS + o];
      d[0]      = bfu(u.x & 0xffff); d[GS]     = bfu(u.x >> 16);
      d[2 * GS] = bfu(u.y & 0xffff); d[3 * GS] = bfu(u.y >> 16);
      d[4 * GS] = bfu(u.z & 0xffff); d[5 * GS] = bfu(u.z >> 16);
      d[6 * GS] = bfu(u.w & 0xffff); d[7 * GS] = bfu(u.w >> 16);
    }
  } else {
    const float4* s4 = (const float4*)src;        // 12288 f32 = 3072 float4
    for (int k = t; k < 3072; k += 256) {
      float4 v = s4[k];
      int e = k << 2; int o = e >> 6, f = e & 63; // 4 elems share o, f..f+3
      float* d = &dst[f * GS + o];
      d[0] = v.x; d[GS] = v.y; d[2 * GS] = v.z; d[3 * GS] = v.w;
    }
  }
}

__global__ void k_gru(const float* __restrict__ xt, const void* h0g, const void* wihg,
                      const void* whhg, const void* bihg, const void* bhhg,
                      float* __restrict__ Wout, const int* flagp) {
  __shared__ float wb1[64 * GS];   // wih^T  [f][o], 49.4KB
  __shared__ float wb2[64 * GS];   // whh^T  [f][o], 49.4KB
  __shared__ float xtr[256];
  __shared__ float h0r[256];
  int flag = flagp[0];
  int t = threadIdx.x;
  int j0 = blockIdx.x * 4;
  { int jj = t >> 6, f = t & 63;
    xtr[t] = xt[(j0 + jj) * 64 + f];
    h0r[t] = ldf(h0g, (j0 + jj) * 64 + f, flag); }
  stage_w(wihg, wb1, flag, t);
  stage_w(whhg, wb2, flag, t);
  __syncthreads();
  int jl = t >> 6, c2 = t & 63;
  float xr = 0, xz = 0, xn = 0, hr = 0, hz = 0, hn = 0;
#pragma unroll 4
  for (int f = 0; f < 64; f++) {
    float xv = xtr[jl * 64 + f];
    float hv = h0r[jl * 64 + f];
    const float* w1 = &wb1[f * GS];
    const float* w2 = &wb2[f * GS];
    xr += xv * w1[c2]; xz += xv * w1[64 + c2]; xn += xv * w1[128 + c2];
    hr += hv * w2[c2]; hz += hv * w2[64 + c2]; hn += hv * w2[128 + c2];
  }
  xr += ldf(bihg, c2, flag); xz += ldf(bihg, 64 + c2, flag); xn += ldf(bihg, 128 + c2, flag);
  hr += ldf(bhhg, c2, flag); hz += ldf(bhhg, 64 + c2, flag); hn += ldf(bhhg, 128 + c2, flag);
  float rg = 1.f / (1.f + expf(-(xr + hr)));
  float zg = 1.f / (1.f + expf(-(xz + hz)));
  float nc = tanhf(xn + rg * hn);
  Wout[(j0 + jl) * 64 + c2] = (1.f - zg) * nc + zg * h0r[jl * 64 + c2];
}

// ---- tail stage 1: g[o] = pooled @ gnn_fc_w.T + gnn_fc_b  (64 blocks) ----
__global__ void k_g(const float* __restrict__ svec, const float* __restrict__ Wm,
                    const void* gw, const void* gb, float* __restrict__ g,
                    const int* flagp) {
  __shared__ float pooled[64];
  int flag = flagp[0];
  int t = threadIdx.x, w = t >> 6, lane = t & 63;
  if (t < 64) {
    float a = 0.f;
    for (int f = 0; f < 64; f++) a += svec[f] * Wm[f * 64 + t];
    pooled[t] = a * (1.0f / (float)NN);
  }
  __syncthreads();
  int o = blockIdx.x * 4 + w;      // 0..255
  float acc = pooled[lane] * ldf(gw, o * 64 + lane, flag);
  acc = wsum(acc);
  if (lane == 0) g[o] = acc + ldf(gb, o, flag);
}

// ---- tail stage 2: layernorm over [g | d] -> lnv (1 block, tiny traffic) ----
__global__ void k_ln(const float* __restrict__ g, const float* __restrict__ d,
                     const void* lng, const void* lnb, float* __restrict__ lnv,
                     const int* flagp) {
  __shared__ float red[256];
  __shared__ float stats[2];
  int flag = flagp[0];
  int t = threadIdx.x;
  float v0 = g[t], v1 = d[t];
  red[t] = v0 + v1; __syncthreads();
  for (int s = 128; s > 0; s >>= 1) { if (t < s) red[t] += red[t + s]; __syncthreads(); }
  if (t == 0) stats[0] = red[0];
  __syncthreads();
  red[t] = v0 * v0 + v1 * v1; __syncthreads();
  for (int s = 128; s > 0; s >>= 1) { if (t < s) red[t] += red[t + s]; __syncthreads(); }
  if (t == 0) stats[1] = red[0];
  __syncthreads();
  float mu = stats[0] * (1.f / 512.f);
  float var = stats[1] * (1.f / 512.f) - mu * mu;
  float istd = rsqrtf(var + 1e-5f);
  lnv[t]       = (v0 - mu) * istd * ldf(lng, t, flag)       + ldf(lnb, t, flag);
  lnv[t + 256] = (v1 - mu) * istd * ldf(lng, t + 256, flag) + ldf(lnb, t + 256, flag);
}

// ---- tail stage 3: h1 = relu(lnv @ fusion_w.T + fb) (64 blocks, uint4 row loads) ----
__global__ void k_fuse(const float* __restrict__ lnv, const void* fw, const void* fb,
                       float* __restrict__ h1, const int* flagp) {
  __shared__ float lv[512];
  int flag = flagp[0];
  int t = threadIdx.x, w = t >> 6, lane = t & 63;
  lv[t] = lnv[t]; lv[t + 256] = lnv[t + 256];
  __syncthreads();
  int o = blockIdx.x * 4 + w;      // 0..255
  float acc = 0.f;
  if (flag) {
    uint4 u = *((const uint4*)((const unsigned short*)fw + o * 512) + lane);  // 8 bf16
    const float* l = &lv[lane * 8];
    acc = bfu(u.x & 0xffff) * l[0] + bfu(u.x >> 16) * l[1]
        + bfu(u.y & 0xffff) * l[2] + bfu(u.y >> 16) * l[3]
        + bfu(u.z & 0xffff) * l[4] + bfu(u.z >> 16) * l[5]
        + bfu(u.w & 0xffff) * l[6] + bfu(u.w >> 16) * l[7];
  } else {
    const float4* fv = (const float4*)((const float*)fw + o * 512);
    float4 a = fv[lane * 2], b = fv[lane * 2 + 1];
    const float* l = &lv[lane * 8];
    acc = a.x * l[0] + a.y * l[1] + a.z * l[2] + a.w * l[3]
        + b.x * l[4] + b.y * l[5] + b.z * l[6] + b.w * l[7];
  }
  acc = wsum(acc);
  if (lane == 0) h1[o] = fmaxf(acc + ldf(fb, o, flag), 0.0f);
}

// ---- tail stage 4: task + time heads (5 blocks) ----
__global__ void k_out(const float* __restrict__ h1, const void* tw, const void* tb,
                      const void* tmw, const void* tmb, void* out, const int* flagp) {
  int flag = flagp[0];
  int t = threadIdx.x, w = t >> 6, lane = t & 63;
  int o = blockIdx.x * 4 + w;
  if (o >= 17) return;
  float acc = 0.f;
  if (o < 16) { for (int k = lane; k < 256; k += 64) acc += h1[k] * ldf(tw, o * 256 + k, flag); }
  else        { for (int k = lane; k < 256; k += 64) acc += h1[k] * ldf(tmw, k, flag); }
  acc = wsum(acc);
  if (lane == 0) {
    float bias = (o < 16) ? ldf(tb, o, flag) : ldf(tmb, 0, flag);
    stf(out, o, acc + bias, flag);
  }
}

extern "C" void kernel_launch(void* const* d_in, const int* in_sizes, int n_in,
                              void* d_out, int out_size, void* d_ws, size_t ws_size,
                              hipStream_t stream) {
  const void* x    = d_in[0];
  const int*  ei   = (const int*)d_in[1];
  const void* docf = d_in[2];
  const void* pw   = d_in[3];
  const void* h0   = d_in[4];
  const void* wih  = d_in[5];
  const void* whh  = d_in[6];
  const void* bih  = d_in[7];
  const void* bhh  = d_in[8];
  const void* gw   = d_in[9];
  const void* gb   = d_in[10];
  const void* dw   = d_in[11];
  const void* db   = d_in[12];
  const void* lng  = d_in[13];
  const void* lnb  = d_in[14];
  const void* fw   = d_in[15];
  const void* fb   = d_in[16];
  const void* tw   = d_in[17];
  const void* tb   = d_in[18];
  const void* tmw  = d_in[19];
  const void* tmb  = d_in[20];

  const int* row = ei;
  const int* col = ei + EE;

  float* wsf = (float*)d_ws;
  int*   wsi = (int*)d_ws;

  hipMemsetAsync(wsi + P_PART, 0, (size_t)PZERO_LEN * 4, stream);   // degm + partm
  hipMemsetAsync(wsi + P_CANDN, 0, (size_t)ZERO_LEN * 4, stream);
  k_detect<<<1, 256, 0, stream>>>((const unsigned short*)x, wsi + P_FLAG);
  k_hcol<<<NBC * CCC, HTH, 0, stream>>>(col, (unsigned*)(wsi + P_DEGM));
  k_redA<<<NDBLK + 64, 256, 0, stream>>>((const unsigned*)(wsi + P_DEGM), wsf + P_DIS,
                                         docf, dw, db, wsf + P_D, wsi + P_FLAG);
  k_hrow<<<NBR * CCR, HTH, 0, stream>>>(row, col, wsf + P_DIS, wsf + P_PARTM);
  k_redB<<<NDBLK, 256, 0, stream>>>(wsf + P_PARTM, wsf + P_DIS, wsf + P_C);
  k_x<<<XBLOCKS, 256, 0, stream>>>(x, pw, wsf + P_C, wsf + P_SCORE,
                                   wsf + P_S8, wsi + P_FLAG);
  k_hist<<<HB, 1024, 0, stream>>>(wsf + P_SCORE, (unsigned*)(wsi + P_PART));
  k_redH<<<HW / 256, 256, 0, stream>>>((const unsigned*)(wsi + P_PART), wsi + P_HIST);
  k_thresh<<<1, 256, 0, stream>>>(wsi + P_HIST, wsi + P_THR, wsf + P_S8, wsf + P_SV);
  k_collect<<<NDBLK, 256, 0, stream>>>(wsf + P_SCORE, wsi + P_THR, wsi + P_CANDN,
                                       (unsigned*)(wsi + P_CKEY), wsi + P_CIDX);
  k_top<<<1, 256, 0, stream>>>(wsi + P_CANDN, (const unsigned*)(wsi + P_CKEY),
                               wsi + P_CIDX, x, wsf + P_XT, wsi + P_FLAG);
  k_gru<<<16, 256, 0, stream>>>(wsf + P_XT, h0, wih, whh, bih, bhh, wsf + P_WW, wsi + P_FLAG);
  k_g<<<64, 256, 0, stream>>>(wsf + P_SV, wsf + P_WW, gw, gb, wsf + P_G, wsi + P_FLAG);
  k_ln<<<1, 256, 0, stream>>>(wsf + P_G, wsf + P_D, lng, lnb, wsf + P_LNV, wsi + P_FLAG);
  k_fuse<<<64, 256, 0, stream>>>(wsf + P_LNV, fw, fb, wsf + P_H1, wsi + P_FLAG);
  k_out<<<5, 256, 0, stream>>>(wsf + P_H1, tw, tb, tmw, tmb, d_out, wsi + P_FLAG);
}